// Round 1
// baseline (566.317 us; speedup 1.0000x reference)
//
#include <hip/hip_runtime.h>
#include <hip/hip_bf16.h>

// Problem constants
#define B_      16
#define C_      256
#define H_      56
#define W_      56
#define HW_     3136          // 56*56
#define G_      64            // windows per image
#define P_      49            // tokens per window
#define NTOK    50176         // B*G*P
#define HEADS_  8
#define DH_     32
#define SCALE_  0.0625f       // 256^-0.5
#define EPS_    1e-5f

typedef short bf16x8 __attribute__((ext_vector_type(8)));
typedef float f32x4  __attribute__((ext_vector_type(4)));
using bf16 = __hip_bfloat16;

__device__ __forceinline__ void gload16(const void* g, void* l) {
  __builtin_amdgcn_global_load_lds((const __attribute__((address_space(1))) void*)g,
                                   (__attribute__((address_space(3))) void*)l, 16, 0, 0);
}

// token t -> (batch, hh, ww)
__device__ __forceinline__ void tok_decode(int t, int& b, int& hh, int& ww) {
  b = t / HW_;
  int rr  = t - b * HW_;
  int win = rr / P_;
  int p   = rr - win * P_;
  int ph  = p / 7;
  int pw  = p - ph * 7;
  hh = (win >> 3) * 7 + ph;   // gh*7+ph
  ww = (win & 7) * 7 + pw;    // gw*7+pw
}

// ---------------------------------------------------------------------------
// prep: transpose weights to [N][K] bf16, gather attention bias [H][P][P]
// ---------------------------------------------------------------------------
__global__ __launch_bounds__(256)
void prep_kernel(const float* __restrict__ wqkv, const float* __restrict__ wmerge,
                 const float* __restrict__ w1, const float* __restrict__ w2,
                 const float* __restrict__ btab, const int* __restrict__ relidx,
                 bf16* __restrict__ wqkvT, bf16* __restrict__ wmergeT,
                 bf16* __restrict__ w1T, bf16* __restrict__ w2T,
                 float* __restrict__ battn)
{
  int idx = blockIdx.x * 256 + threadIdx.x;
  if (idx < 196608) {                       // wqkv [256][768] -> [768][256]
    int n = idx >> 8, k = idx & 255;
    wqkvT[idx] = __float2bfloat16(wqkv[k * 768 + n]);
    return;
  }
  idx -= 196608;
  if (idx < 65536) {                        // wmerge [256][256] -> [256][256]T
    int n = idx >> 8, k = idx & 255;
    wmergeT[idx] = __float2bfloat16(wmerge[k * 256 + n]);
    return;
  }
  idx -= 65536;
  if (idx < 262144) {                       // w1 [256][1024] -> [1024][256]
    int n = idx >> 8, k = idx & 255;
    w1T[idx] = __float2bfloat16(w1[k * 1024 + n]);
    return;
  }
  idx -= 262144;
  if (idx < 262144) {                       // w2 [1024][256] -> [256][1024]
    int n = idx >> 10, k = idx & 1023;
    w2T[idx] = __float2bfloat16(w2[k * 256 + n]);
    return;
  }
  idx -= 262144;
  if (idx < HEADS_ * P_ * P_) {             // battn[h][i][j] = btab[relidx[i][j]][h]
    int h  = idx / (P_ * P_);
    int ij = idx - h * (P_ * P_);
    battn[idx] = btab[relidx[ij] * HEADS_ + h];
  }
}

// ---------------------------------------------------------------------------
// LN1: gather x (partition) + layernorm over C -> y bf16 [NTOK][C]
// one wave per token, lane handles channels lane+64j
// ---------------------------------------------------------------------------
__global__ __launch_bounds__(256)
void ln1_kernel(const float* __restrict__ x, const float* __restrict__ gam,
                const float* __restrict__ bet, bf16* __restrict__ y)
{
  const int t    = blockIdx.x * 4 + (threadIdx.x >> 6);
  const int lane = threadIdx.x & 63;
  int tb, hh, ww;
  tok_decode(t, tb, hh, ww);
  const float* xb = x + (size_t)tb * (C_ * HW_) + hh * W_ + ww;
  float v[4];
#pragma unroll
  for (int j = 0; j < 4; j++) v[j] = xb[(size_t)(lane + 64 * j) * HW_];
  float sum = v[0] + v[1] + v[2] + v[3];
  float sq  = v[0]*v[0] + v[1]*v[1] + v[2]*v[2] + v[3]*v[3];
#pragma unroll
  for (int off = 32; off > 0; off >>= 1) {
    sum += __shfl_xor(sum, off, 64);
    sq  += __shfl_xor(sq,  off, 64);
  }
  float mu  = sum * (1.0f / 256.0f);
  float var = sq * (1.0f / 256.0f) - mu * mu;
  float rs  = rsqrtf(var + EPS_);
#pragma unroll
  for (int j = 0; j < 4; j++) {
    int c = lane + 64 * j;
    y[(size_t)t * C_ + c] = __float2bfloat16((v[j] - mu) * rs * gam[c] + bet[c]);
  }
}

// LN2: same but coalesced fp32 token-major input
__global__ __launch_bounds__(256)
void ln2_kernel(const float* __restrict__ xw, const float* __restrict__ gam,
                const float* __restrict__ bet, bf16* __restrict__ z)
{
  const int t    = blockIdx.x * 4 + (threadIdx.x >> 6);
  const int lane = threadIdx.x & 63;
  const float* xb = xw + (size_t)t * C_;
  float v[4];
#pragma unroll
  for (int j = 0; j < 4; j++) v[j] = xb[lane + 64 * j];
  float sum = v[0] + v[1] + v[2] + v[3];
  float sq  = v[0]*v[0] + v[1]*v[1] + v[2]*v[2] + v[3]*v[3];
#pragma unroll
  for (int off = 32; off > 0; off >>= 1) {
    sum += __shfl_xor(sum, off, 64);
    sq  += __shfl_xor(sq,  off, 64);
  }
  float mu  = sum * (1.0f / 256.0f);
  float var = sq * (1.0f / 256.0f) - mu * mu;
  float rs  = rsqrtf(var + EPS_);
#pragma unroll
  for (int j = 0; j < 4; j++) {
    int c = lane + 64 * j;
    z[(size_t)t * C_ + c] = __float2bfloat16((v[j] - mu) * rs * gam[c] + bet[c]);
  }
}

// ---------------------------------------------------------------------------
// attention: one block (64 threads) per (b,g,head). fp32 VALU, P=49.
// qkv: bf16 [NTOK][768] (q|k|v, each c = h*32+d). out: bf16 [NTOK][256]
// ---------------------------------------------------------------------------
__global__ __launch_bounds__(64)
void attn_kernel(const bf16* __restrict__ qkv, const float* __restrict__ battn,
                 bf16* __restrict__ out)
{
  __shared__ float Qs[P_][33], Ks[P_][33], Vs[P_][33];
  const int bid  = blockIdx.x;
  const int h    = bid & 7;
  const int wg   = bid >> 3;          // b*G+g
  const int t0   = wg * P_;
  const int lane = threadIdx.x;
  const size_t qbase = (size_t)t0 * 768 + h * DH_;
  for (int idx = lane; idx < P_ * DH_; idx += 64) {
    int i = idx >> 5, d = idx & 31;
    size_t ro = qbase + (size_t)i * 768 + d;
    Qs[i][d] = __bfloat162float(qkv[ro]);
    Ks[i][d] = __bfloat162float(qkv[ro + 256]) * SCALE_;
    Vs[i][d] = __bfloat162float(qkv[ro + 512]);
  }
  __syncthreads();
  if (lane < P_) {
    float q[DH_];
#pragma unroll
    for (int d = 0; d < DH_; d++) q[d] = Qs[lane][d];
    const float* bptr = battn + h * (P_ * P_) + lane * P_;
    float s[P_];
    float m = -1e30f;
#pragma unroll
    for (int j = 0; j < P_; j++) {
      float acc = bptr[j];
#pragma unroll
      for (int d = 0; d < DH_; d++) acc += q[d] * Ks[j][d];
      s[j] = acc;
      m = fmaxf(m, acc);
    }
    float sum = 0.f;
#pragma unroll
    for (int j = 0; j < P_; j++) { float p = __expf(s[j] - m); s[j] = p; sum += p; }
    float inv = 1.0f / sum;
    float o[DH_];
#pragma unroll
    for (int d = 0; d < DH_; d++) o[d] = 0.f;
#pragma unroll
    for (int j = 0; j < P_; j++) {
      float p = s[j];
#pragma unroll
      for (int d = 0; d < DH_; d++) o[d] += p * Vs[j][d];
    }
    bf16* op = out + (size_t)(t0 + lane) * C_ + h * DH_;
#pragma unroll
    for (int d = 0; d < DH_; d++) op[d] = __float2bfloat16(o[d] * inv);
  }
}

// ---------------------------------------------------------------------------
// GEMM: out[M,N] = A[M,K](bf16) @ Wt[N,K](bf16)^T + bias, 128x128 tile,
// 4 waves 2x2, 4x4 frags of 16x16x32 MFMA, global_load_lds staging (m97 recipe)
// EPI 0: store bf16 (qkv)     EPI 1: gelu -> bf16 (mlp1)
// EPI 2: + x-residual(gather) -> fp32 xw2   EPI 3: + xw2 residual -> scatter d_out
// ---------------------------------------------------------------------------
template<int EPI>
__global__ __launch_bounds__(256)
void gemm_kernel(const bf16* __restrict__ A, const bf16* __restrict__ Wt,
                 const float* __restrict__ bias,
                 int N, int K, int row0,
                 bf16* __restrict__ outb, float* __restrict__ outf,
                 const float* __restrict__ res)
{
  __shared__ __align__(16) bf16 As[128 * 32];
  __shared__ __align__(16) bf16 Bs[128 * 32];
  const int tid  = threadIdx.x;
  const int lane = tid & 63;
  const int wave = tid >> 6;
  const int wr = wave >> 1, wc = wave & 1;
  const int bm = blockIdx.y * 128, bn = blockIdx.x * 128;

  f32x4 acc[4][4] = {};

  const int trow = tid >> 2;            // 0..63
  const int tcol = (tid & 3) * 8;       // 0,8,16,24
  const bf16* aA0 = A  + (size_t)(bm + trow) * K + tcol;
  const bf16* aA1 = A  + (size_t)(bm + 64 + trow) * K + tcol;
  const bf16* aB0 = Wt + (size_t)(bn + trow) * K + tcol;
  const bf16* aB1 = Wt + (size_t)(bn + 64 + trow) * K + tcol;
  bf16* dA0 = As + tid * 8;
  bf16* dA1 = As + 2048 + tid * 8;
  bf16* dB0 = Bs + tid * 8;
  bf16* dB1 = Bs + 2048 + tid * 8;

  const int kc16 = (lane >> 4) * 8;
  const int rA = wr * 64 + (lane & 15);
  const int rB = wc * 64 + (lane & 15);

  for (int k0 = 0; k0 < K; k0 += 32) {
    gload16(aA0 + k0, dA0);
    gload16(aA1 + k0, dA1);
    gload16(aB0 + k0, dB0);
    gload16(aB1 + k0, dB1);
    __syncthreads();
    bf16x8 af[4], bfr[4];
#pragma unroll
    for (int i = 0; i < 4; i++) {
      af[i]  = *(const bf16x8*)(As + (rA + i * 16) * 32 + kc16);
      bfr[i] = *(const bf16x8*)(Bs + (rB + i * 16) * 32 + kc16);
    }
#pragma unroll
    for (int mi = 0; mi < 4; mi++)
#pragma unroll
      for (int ni = 0; ni < 4; ni++)
        acc[mi][ni] = __builtin_amdgcn_mfma_f32_16x16x32_bf16(af[mi], bfr[ni], acc[mi][ni], 0, 0, 0);
    __syncthreads();
  }

#pragma unroll
  for (int mi = 0; mi < 4; mi++) {
#pragma unroll
    for (int ni = 0; ni < 4; ni++) {
#pragma unroll
      for (int r = 0; r < 4; r++) {
        const int row = bm + wr * 64 + mi * 16 + (lane >> 4) * 4 + r;
        const int col = bn + wc * 64 + ni * 16 + (lane & 15);
        float v = acc[mi][ni][r] + bias[col];
        if (EPI == 0) {
          outb[(size_t)row * N + col] = __float2bfloat16(v);
        } else if (EPI == 1) {
          float gv = 0.5f * v * (1.0f + erff(v * 0.70710678118f));
          outb[(size_t)row * N + col] = __float2bfloat16(gv);
        } else if (EPI == 2) {
          int tb, hh, ww;
          tok_decode(row, tb, hh, ww);
          float xg = res[((size_t)tb * C_ + col) * HW_ + hh * W_ + ww];
          outf[(size_t)row * C_ + col] = xg + v;
        } else {
          int t = row0 + row;
          int tb, hh, ww;
          tok_decode(t, tb, hh, ww);
          float prev = res[(size_t)row * C_ + col];
          outf[((size_t)tb * C_ + col) * HW_ + hh * W_ + ww] = prev + v;
        }
      }
    }
  }
}

// ---------------------------------------------------------------------------
extern "C" void kernel_launch(void* const* d_in, const int* in_sizes, int n_in,
                              void* d_out, int out_size, void* d_ws, size_t ws_size,
                              hipStream_t stream)
{
  const float* x      = (const float*)d_in[0];
  const float* ln1_g  = (const float*)d_in[1];
  const float* ln1_b  = (const float*)d_in[2];
  const float* wqkv   = (const float*)d_in[3];
  const float* bqkv   = (const float*)d_in[4];
  const float* wmerge = (const float*)d_in[5];
  const float* bmerge = (const float*)d_in[6];
  const float* btab   = (const float*)d_in[7];
  const float* ln2_g  = (const float*)d_in[8];
  const float* ln2_b  = (const float*)d_in[9];
  const float* w1     = (const float*)d_in[10];
  const float* b1     = (const float*)d_in[11];
  const float* w2     = (const float*)d_in[12];
  const float* b2     = (const float*)d_in[13];
  const int*   relidx = (const int*)d_in[14];
  float* out = (float*)d_out;

  char* ws = (char*)d_ws;
  // workspace layout (peak 104,410,368 bytes ≈ 99.6 MB)
  bf16*  wqkvT   = (bf16*)(ws);                         // 393216
  bf16*  wmergeT = (bf16*)(ws + 393216);                // 131072
  bf16*  w1T     = (bf16*)(ws + 524288);                // 524288
  bf16*  w2T     = (bf16*)(ws + 1048576);               // 524288
  float* battn   = (float*)(ws + 1572864);              // 76832 (pad->1649920)
  bf16*  ybuf    = (bf16*)(ws + 1649920);               // 25690112  (y / attn-out / z)
  bf16*  qkvbuf  = (bf16*)(ws + 27340032);              // 77070336  (qkv)
  float* xw2     = (float*)(ws + 27340032);             // 51380224  (aliases qkv after attn)
  bf16*  hbuf    = (bf16*)(ws + 78720256);              // 25690112  (mlp hidden chunk)

  prep_kernel<<<3148, 256, 0, stream>>>(wqkv, wmerge, w1, w2, btab, relidx,
                                        wqkvT, wmergeT, w1T, w2T, battn);

  // partition + LN1 -> y
  ln1_kernel<<<NTOK / 4, 256, 0, stream>>>(x, ln1_g, ln1_b, ybuf);

  // qkv = y @ wqkv + bqkv
  gemm_kernel<0><<<dim3(6, 392), 256, 0, stream>>>(ybuf, wqkvT, bqkv, 768, 256, 0,
                                                   qkvbuf, nullptr, nullptr);

  // windowed attention -> attn-out (reuse ybuf)
  attn_kernel<<<8192, 64, 0, stream>>>(qkvbuf, battn, ybuf);

  // merge proj + x residual -> xw2 (fp32, overwrites dead qkv region)
  gemm_kernel<2><<<dim3(2, 392), 256, 0, stream>>>(ybuf, wmergeT, bmerge, 256, 256, 0,
                                                   nullptr, xw2, x);

  // LN2 -> z (reuse ybuf)
  ln2_kernel<<<NTOK / 4, 256, 0, stream>>>(xw2, ln2_g, ln2_b, ybuf);

  // MLP in 4 token-chunks of 12544 (bounds ws usage)
  for (int c = 0; c < 4; ++c) {
    int r0 = c * 12544;
    gemm_kernel<1><<<dim3(8, 98), 256, 0, stream>>>(ybuf + (size_t)r0 * C_, w1T, b1,
                                                    1024, 256, r0, hbuf, nullptr, nullptr);
    gemm_kernel<3><<<dim3(2, 98), 256, 0, stream>>>(hbuf, w2T, b2,
                                                    256, 1024, r0, nullptr, out,
                                                    xw2 + (size_t)r0 * C_);
  }
}

// Round 2
// 488.001 us; speedup vs baseline: 1.1605x; 1.1605x over previous
//
#include <hip/hip_runtime.h>
#include <hip/hip_bf16.h>

// Problem constants
#define B_      16
#define C_      256
#define H_      56
#define W_      56
#define HW_     3136          // 56*56
#define G_      64            // windows per image
#define P_      49            // tokens per window
#define NTOK    50176         // B*G*P
#define HEADS_  8
#define DH_     32
#define SCALE_  0.0625f       // 256^-0.5
#define EPS_    1e-5f

typedef short bf16x8 __attribute__((ext_vector_type(8)));
typedef short bf16x4_t __attribute__((ext_vector_type(4)));
typedef float f32x4  __attribute__((ext_vector_type(4)));
using bf16 = __hip_bfloat16;

__device__ __forceinline__ void gload16(const void* g, void* l) {
  __builtin_amdgcn_global_load_lds((const __attribute__((address_space(1))) void*)g,
                                   (__attribute__((address_space(3))) void*)l, 16, 0, 0);
}

__device__ __forceinline__ float b2f(short s) {
  union { float f; unsigned u; } v; v.u = ((unsigned)(unsigned short)s) << 16; return v.f;
}
__device__ __forceinline__ short f2b(float f) {   // RNE, matches __float2bfloat16
  union { float f; unsigned u; } v; v.f = f;
  unsigned r = (v.u + 0x7FFFu + ((v.u >> 16) & 1u)) >> 16;
  return (short)r;
}

// token t -> (batch, hh, ww)
__device__ __forceinline__ void tok_decode(int t, int& b, int& hh, int& ww) {
  b = t / HW_;
  int rr  = t - b * HW_;
  int win = rr / P_;
  int p   = rr - win * P_;
  int ph  = p / 7;
  int pw  = p - ph * 7;
  hh = (win >> 3) * 7 + ph;   // gh*7+ph
  ww = (win & 7) * 7 + pw;    // gw*7+pw
}

// ---------------------------------------------------------------------------
// prep: transpose weights to [N][K] bf16, repack attention bias to
// bt[h][key(64)][q*4+qni] bf16  (query = qni*16+q), zero-padded
// ---------------------------------------------------------------------------
__global__ __launch_bounds__(256)
void prep_kernel(const float* __restrict__ wqkv, const float* __restrict__ wmerge,
                 const float* __restrict__ w1, const float* __restrict__ w2,
                 const float* __restrict__ btab, const int* __restrict__ relidx,
                 bf16* __restrict__ wqkvT, bf16* __restrict__ wmergeT,
                 bf16* __restrict__ w1T, bf16* __restrict__ w2T,
                 short* __restrict__ bt)
{
  int idx = blockIdx.x * 256 + threadIdx.x;
  if (idx < 196608) {                       // wqkv [256][768] -> [768][256]
    int n = idx >> 8, k = idx & 255;
    wqkvT[idx] = __float2bfloat16(wqkv[k * 768 + n]);
    return;
  }
  idx -= 196608;
  if (idx < 65536) {                        // wmerge [256][256] -> [256][256]T
    int n = idx >> 8, k = idx & 255;
    wmergeT[idx] = __float2bfloat16(wmerge[k * 256 + n]);
    return;
  }
  idx -= 65536;
  if (idx < 262144) {                       // w1 [256][1024] -> [1024][256]
    int n = idx >> 8, k = idx & 255;
    w1T[idx] = __float2bfloat16(w1[k * 1024 + n]);
    return;
  }
  idx -= 262144;
  if (idx < 262144) {                       // w2 [1024][256] -> [256][1024]
    int n = idx >> 10, k = idx & 1023;
    w2T[idx] = __float2bfloat16(w2[k * 256 + n]);
    return;
  }
  idx -= 262144;
  if (idx < 32768) {                        // bt[h][key][q*4+qni]
    int h    = idx >> 12;
    int rest = idx & 4095;
    int key  = rest >> 6;
    int col  = rest & 63;
    int q    = col >> 2, qni = col & 3;
    int query = qni * 16 + q;
    float v = 0.f;
    if (key < P_ && query < P_) v = btab[relidx[query * P_ + key] * HEADS_ + h];
    bt[idx] = f2b(v);
  }
}

// ---------------------------------------------------------------------------
// LN1: gather x (partition) + layernorm over C -> y bf16 [NTOK][C]
// ---------------------------------------------------------------------------
__global__ __launch_bounds__(256)
void ln1_kernel(const float* __restrict__ x, const float* __restrict__ gam,
                const float* __restrict__ bet, bf16* __restrict__ y)
{
  const int t    = blockIdx.x * 4 + (threadIdx.x >> 6);
  const int lane = threadIdx.x & 63;
  int tb, hh, ww;
  tok_decode(t, tb, hh, ww);
  const float* xb = x + (size_t)tb * (C_ * HW_) + hh * W_ + ww;
  float v[4];
#pragma unroll
  for (int j = 0; j < 4; j++) v[j] = xb[(size_t)(lane + 64 * j) * HW_];
  float sum = v[0] + v[1] + v[2] + v[3];
  float sq  = v[0]*v[0] + v[1]*v[1] + v[2]*v[2] + v[3]*v[3];
#pragma unroll
  for (int off = 32; off > 0; off >>= 1) {
    sum += __shfl_xor(sum, off, 64);
    sq  += __shfl_xor(sq,  off, 64);
  }
  float mu  = sum * (1.0f / 256.0f);
  float var = sq * (1.0f / 256.0f) - mu * mu;
  float rs  = rsqrtf(var + EPS_);
#pragma unroll
  for (int j = 0; j < 4; j++) {
    int c = lane + 64 * j;
    y[(size_t)t * C_ + c] = __float2bfloat16((v[j] - mu) * rs * gam[c] + bet[c]);
  }
}

__global__ __launch_bounds__(256)
void ln2_kernel(const float* __restrict__ xw, const float* __restrict__ gam,
                const float* __restrict__ bet, bf16* __restrict__ z)
{
  const int t    = blockIdx.x * 4 + (threadIdx.x >> 6);
  const int lane = threadIdx.x & 63;
  const float* xb = xw + (size_t)t * C_;
  float v[4];
#pragma unroll
  for (int j = 0; j < 4; j++) v[j] = xb[lane + 64 * j];
  float sum = v[0] + v[1] + v[2] + v[3];
  float sq  = v[0]*v[0] + v[1]*v[1] + v[2]*v[2] + v[3]*v[3];
#pragma unroll
  for (int off = 32; off > 0; off >>= 1) {
    sum += __shfl_xor(sum, off, 64);
    sq  += __shfl_xor(sq,  off, 64);
  }
  float mu  = sum * (1.0f / 256.0f);
  float var = sq * (1.0f / 256.0f) - mu * mu;
  float rs  = rsqrtf(var + EPS_);
#pragma unroll
  for (int j = 0; j < 4; j++) {
    int c = lane + 64 * j;
    z[(size_t)t * C_ + c] = __float2bfloat16((v[j] - mu) * rs * gam[c] + bet[c]);
  }
}

// ---------------------------------------------------------------------------
// attention (MFMA): one wave per (window, head).
// S^T = K·Q^T via 16x16x32 bf16 MFMA (49 padded to 64), softmax per query
// column fully in-register, P normalized, LDS round-trip to A-frag layout,
// O = P·V with V B-frags loaded early from global.
// qkv: bf16 [NTOK][768]; bt: bf16 [8][64][64]; out: bf16 [NTOK][256]
// ---------------------------------------------------------------------------
__global__ __launch_bounds__(64)
void attn_kernel(const short* __restrict__ qkv, const short* __restrict__ bt,
                 short* __restrict__ out)
{
  __shared__ short Pbuf[64 * 72];
  const int bid  = blockIdx.x;
  const int h    = bid & 7;
  const int wg   = bid >> 3;
  const int t0   = wg * P_;
  const int lane = threadIdx.x;
  const int g = lane >> 4, q = lane & 15;

  const short* qb = qkv + (size_t)t0 * 768 + h * 32;

  // V B-frags: vf[kkt][n2] lane holds V[key kkt*32+8g+jj][dim n2*16+q].
  // Issued first so latency hides under QK^T + softmax.
  bf16x8 vf[2][2];
#pragma unroll
  for (int kkt = 0; kkt < 2; kkt++)
#pragma unroll
    for (int n2 = 0; n2 < 2; n2++)
#pragma unroll
      for (int jj = 0; jj < 8; jj++) {
        int key = kkt * 32 + 8 * g + jj; key = key > 48 ? 48 : key;
        vf[kkt][n2][jj] = qb[(size_t)key * 768 + 512 + n2 * 16 + q];
      }

  // K A-frags (rows=keys) and Q B-frags (cols=queries), direct 16B loads
  bf16x8 kf[4], qf[4];
#pragma unroll
  for (int mi = 0; mi < 4; mi++) {
    int r_ = mi * 16 + q; r_ = r_ > 48 ? 48 : r_;
    kf[mi] = *(const bf16x8*)(qb + (size_t)r_ * 768 + 256 + 8 * g);
  }
#pragma unroll
  for (int ni = 0; ni < 4; ni++) {
    int r_ = ni * 16 + q; r_ = r_ > 48 ? 48 : r_;
    qf[ni] = *(const bf16x8*)(qb + (size_t)r_ * 768 + 8 * g);
  }

  // S^T[key][query]: acc row = key = mi*16+4g+r, col = query = ni*16+q
  f32x4 sacc[4][4] = {};
#pragma unroll
  for (int mi = 0; mi < 4; mi++)
#pragma unroll
    for (int ni = 0; ni < 4; ni++)
      sacc[mi][ni] = __builtin_amdgcn_mfma_f32_16x16x32_bf16(kf[mi], qf[ni], sacc[mi][ni], 0, 0, 0);

  // scale + bias + mask, per-query-column max
  float mx[4] = {-1e30f, -1e30f, -1e30f, -1e30f};
  const short* btb = bt + (size_t)(h * 64) * 64 + q * 4;
#pragma unroll
  for (int mi = 0; mi < 4; mi++)
#pragma unroll
    for (int r = 0; r < 4; r++) {
      int key = mi * 16 + 4 * g + r;
      bf16x4_t bv = *(const bf16x4_t*)(btb + key * 64);
      bool valid = key < P_;
#pragma unroll
      for (int ni = 0; ni < 4; ni++) {
        float s = valid ? fmaf(sacc[mi][ni][r], SCALE_, b2f(bv[ni])) : -1e30f;
        sacc[mi][ni][r] = s;
        mx[ni] = fmaxf(mx[ni], s);
      }
    }
#pragma unroll
  for (int ni = 0; ni < 4; ni++) {
    mx[ni] = fmaxf(mx[ni], __shfl_xor(mx[ni], 16, 64));
    mx[ni] = fmaxf(mx[ni], __shfl_xor(mx[ni], 32, 64));
  }
  float sm[4] = {0.f, 0.f, 0.f, 0.f};
#pragma unroll
  for (int mi = 0; mi < 4; mi++)
#pragma unroll
    for (int ni = 0; ni < 4; ni++)
#pragma unroll
      for (int r = 0; r < 4; r++) {
        float p = __expf(sacc[mi][ni][r] - mx[ni]);
        sacc[mi][ni][r] = p;
        sm[ni] += p;
      }
#pragma unroll
  for (int ni = 0; ni < 4; ni++) {
    sm[ni] += __shfl_xor(sm[ni], 16, 64);
    sm[ni] += __shfl_xor(sm[ni], 32, 64);
    sm[ni] = 1.0f / sm[ni];
  }

  // normalize, pack bf16, store P[query][key] to LDS (row stride 72)
#pragma unroll
  for (int ni = 0; ni < 4; ni++)
#pragma unroll
    for (int mi = 0; mi < 4; mi++) {
      bf16x4_t pv;
#pragma unroll
      for (int r = 0; r < 4; r++) pv[r] = f2b(sacc[mi][ni][r] * sm[ni]);
      *(bf16x4_t*)&Pbuf[(ni * 16 + q) * 72 + mi * 16 + 4 * g] = pv;
    }
  __syncthreads();

  // O = P·V : A-frags of P from LDS, accumulate 4x2 tiles (64 q x 32 d)
  f32x4 oacc[4][2] = {};
#pragma unroll
  for (int kkt = 0; kkt < 2; kkt++) {
    bf16x8 paf[4];
#pragma unroll
    for (int qi = 0; qi < 4; qi++)
      paf[qi] = *(const bf16x8*)&Pbuf[(qi * 16 + q) * 72 + kkt * 32 + 8 * g];
#pragma unroll
    for (int qi = 0; qi < 4; qi++)
#pragma unroll
      for (int n2 = 0; n2 < 2; n2++)
        oacc[qi][n2] = __builtin_amdgcn_mfma_f32_16x16x32_bf16(paf[qi], vf[kkt][n2], oacc[qi][n2], 0, 0, 0);
  }

  short* ob = out + (size_t)t0 * 256 + h * 32;
#pragma unroll
  for (int qi = 0; qi < 4; qi++)
#pragma unroll
    for (int r = 0; r < 4; r++) {
      int query = qi * 16 + 4 * g + r;
      if (query < P_) {
#pragma unroll
        for (int n2 = 0; n2 < 2; n2++)
          ob[(size_t)query * 256 + n2 * 16 + q] = f2b(oacc[qi][n2][r]);
      }
    }
}

// ---------------------------------------------------------------------------
// GEMM: out[M,N] = A[M,K](bf16) @ Wt[N,K](bf16)^T + bias, 128x128 tile,
// 4 waves 2x2, 4x4 frags of 16x16x32 MFMA, global_load_lds staging (m97 recipe)
// EPI 0: store bf16 (qkv)     EPI 1: gelu -> bf16 (mlp1)
// EPI 2: + x-residual(gather) -> fp32 xw2   EPI 3: + xw2 residual -> scatter d_out
// ---------------------------------------------------------------------------
template<int EPI>
__global__ __launch_bounds__(256)
void gemm_kernel(const bf16* __restrict__ A, const bf16* __restrict__ Wt,
                 const float* __restrict__ bias,
                 int N, int K, int row0,
                 bf16* __restrict__ outb, float* __restrict__ outf,
                 const float* __restrict__ res)
{
  __shared__ __align__(16) bf16 As[128 * 32];
  __shared__ __align__(16) bf16 Bs[128 * 32];
  const int tid  = threadIdx.x;
  const int lane = tid & 63;
  const int wave = tid >> 6;
  const int wr = wave >> 1, wc = wave & 1;
  const int bm = blockIdx.y * 128, bn = blockIdx.x * 128;

  f32x4 acc[4][4] = {};

  const int trow = tid >> 2;            // 0..63
  const int tcol = (tid & 3) * 8;       // 0,8,16,24
  const bf16* aA0 = A  + (size_t)(bm + trow) * K + tcol;
  const bf16* aA1 = A  + (size_t)(bm + 64 + trow) * K + tcol;
  const bf16* aB0 = Wt + (size_t)(bn + trow) * K + tcol;
  const bf16* aB1 = Wt + (size_t)(bn + 64 + trow) * K + tcol;
  bf16* dA0 = As + tid * 8;
  bf16* dA1 = As + 2048 + tid * 8;
  bf16* dB0 = Bs + tid * 8;
  bf16* dB1 = Bs + 2048 + tid * 8;

  const int kc16 = (lane >> 4) * 8;
  const int rA = wr * 64 + (lane & 15);
  const int rB = wc * 64 + (lane & 15);

  for (int k0 = 0; k0 < K; k0 += 32) {
    gload16(aA0 + k0, dA0);
    gload16(aA1 + k0, dA1);
    gload16(aB0 + k0, dB0);
    gload16(aB1 + k0, dB1);
    __syncthreads();
    bf16x8 af[4], bfr[4];
#pragma unroll
    for (int i = 0; i < 4; i++) {
      af[i]  = *(const bf16x8*)(As + (rA + i * 16) * 32 + kc16);
      bfr[i] = *(const bf16x8*)(Bs + (rB + i * 16) * 32 + kc16);
    }
#pragma unroll
    for (int mi = 0; mi < 4; mi++)
#pragma unroll
      for (int ni = 0; ni < 4; ni++)
        acc[mi][ni] = __builtin_amdgcn_mfma_f32_16x16x32_bf16(af[mi], bfr[ni], acc[mi][ni], 0, 0, 0);
    __syncthreads();
  }

#pragma unroll
  for (int mi = 0; mi < 4; mi++) {
#pragma unroll
    for (int ni = 0; ni < 4; ni++) {
#pragma unroll
      for (int r = 0; r < 4; r++) {
        const int row = bm + wr * 64 + mi * 16 + (lane >> 4) * 4 + r;
        const int col = bn + wc * 64 + ni * 16 + (lane & 15);
        float v = acc[mi][ni][r] + bias[col];
        if (EPI == 0) {
          outb[(size_t)row * N + col] = __float2bfloat16(v);
        } else if (EPI == 1) {
          float gv = 0.5f * v * (1.0f + erff(v * 0.70710678118f));
          outb[(size_t)row * N + col] = __float2bfloat16(gv);
        } else if (EPI == 2) {
          int tb, hh, ww;
          tok_decode(row, tb, hh, ww);
          float xg = res[((size_t)tb * C_ + col) * HW_ + hh * W_ + ww];
          outf[(size_t)row * C_ + col] = xg + v;
        } else {
          int t = row0 + row;
          int tb, hh, ww;
          tok_decode(t, tb, hh, ww);
          float prev = res[(size_t)row * C_ + col];
          outf[((size_t)tb * C_ + col) * HW_ + hh * W_ + ww] = prev + v;
        }
      }
    }
  }
}

// ---------------------------------------------------------------------------
extern "C" void kernel_launch(void* const* d_in, const int* in_sizes, int n_in,
                              void* d_out, int out_size, void* d_ws, size_t ws_size,
                              hipStream_t stream)
{
  const float* x      = (const float*)d_in[0];
  const float* ln1_g  = (const float*)d_in[1];
  const float* ln1_b  = (const float*)d_in[2];
  const float* wqkv   = (const float*)d_in[3];
  const float* bqkv   = (const float*)d_in[4];
  const float* wmerge = (const float*)d_in[5];
  const float* bmerge = (const float*)d_in[6];
  const float* btab   = (const float*)d_in[7];
  const float* ln2_g  = (const float*)d_in[8];
  const float* ln2_b  = (const float*)d_in[9];
  const float* w1     = (const float*)d_in[10];
  const float* b1     = (const float*)d_in[11];
  const float* w2     = (const float*)d_in[12];
  const float* b2     = (const float*)d_in[13];
  const int*   relidx = (const int*)d_in[14];
  float* out = (float*)d_out;

  char* ws = (char*)d_ws;
  // workspace layout (peak 104,398,848 bytes)
  bf16*  wqkvT   = (bf16*)(ws);                         // 393216
  bf16*  wmergeT = (bf16*)(ws + 393216);                // 131072
  bf16*  w1T     = (bf16*)(ws + 524288);                // 524288
  bf16*  w2T     = (bf16*)(ws + 1048576);               // 524288
  short* battn   = (short*)(ws + 1572864);              // 65536 (bf16 [8][64][64])
  bf16*  ybuf    = (bf16*)(ws + 1638400);               // 25690112  (y / attn-out / z)
  bf16*  qkvbuf  = (bf16*)(ws + 27328512);              // 77070336  (qkv)
  float* xw2     = (float*)(ws + 27328512);             // 51380224  (aliases qkv after attn)
  bf16*  hbuf    = (bf16*)(ws + 78708736);              // 25690112  (mlp hidden chunk)

  prep_kernel<<<3200, 256, 0, stream>>>(wqkv, wmerge, w1, w2, btab, relidx,
                                        wqkvT, wmergeT, w1T, w2T, battn);

  // partition + LN1 -> y
  ln1_kernel<<<NTOK / 4, 256, 0, stream>>>(x, ln1_g, ln1_b, ybuf);

  // qkv = y @ wqkv + bqkv
  gemm_kernel<0><<<dim3(6, 392), 256, 0, stream>>>(ybuf, wqkvT, bqkv, 768, 256, 0,
                                                   qkvbuf, nullptr, nullptr);

  // windowed attention (MFMA) -> attn-out (reuse ybuf)
  attn_kernel<<<8192, 64, 0, stream>>>((const short*)qkvbuf, battn, (short*)ybuf);

  // merge proj + x residual -> xw2 (fp32, overwrites dead qkv region)
  gemm_kernel<2><<<dim3(2, 392), 256, 0, stream>>>(ybuf, wmergeT, bmerge, 256, 256, 0,
                                                   nullptr, xw2, x);

  // LN2 -> z (reuse ybuf)
  ln2_kernel<<<NTOK / 4, 256, 0, stream>>>(xw2, ln2_g, ln2_b, ybuf);

  // MLP in 4 token-chunks of 12544 (bounds ws usage)
  for (int c = 0; c < 4; ++c) {
    int r0 = c * 12544;
    gemm_kernel<1><<<dim3(8, 98), 256, 0, stream>>>(ybuf + (size_t)r0 * C_, w1T, b1,
                                                    1024, 256, r0, hbuf, nullptr, nullptr);
    gemm_kernel<3><<<dim3(2, 98), 256, 0, stream>>>(hbuf, w2T, b2,
                                                    256, 1024, r0, nullptr, out,
                                                    xw2 + (size_t)r0 * C_);
  }
}

// Round 3
// 423.181 us; speedup vs baseline: 1.3382x; 1.1532x over previous
//
#include <hip/hip_runtime.h>
#include <hip/hip_bf16.h>

#define B_      16
#define C_      256
#define H_      56
#define W_      56
#define HW_     3136
#define G_      64
#define P_      49
#define NTOK    50176
#define HEADS_  8
#define DH_     32
#define SCALE_  0.0625f
#define EPS_    1e-5f

typedef short bf16x8 __attribute__((ext_vector_type(8)));
typedef short bf16x4_t __attribute__((ext_vector_type(4)));
typedef float f32x4  __attribute__((ext_vector_type(4)));
using bf16 = __hip_bfloat16;

__device__ __forceinline__ void gload16(const void* g, void* l) {
  __builtin_amdgcn_global_load_lds((const __attribute__((address_space(1))) void*)g,
                                   (__attribute__((address_space(3))) void*)l, 16, 0, 0);
}
__device__ __forceinline__ float b2f(short s) {
  union { float f; unsigned u; } v; v.u = ((unsigned)(unsigned short)s) << 16; return v.f;
}
__device__ __forceinline__ short f2b(float f) {   // RNE
  union { float f; unsigned u; } v; v.f = f;
  unsigned r = (v.u + 0x7FFFu + ((v.u >> 16) & 1u)) >> 16;
  return (short)r;
}

// ---------------------------------------------------------------------------
// prep: weights -> [N][K] bf16; bias -> bt[h][key(64)][q*4+qni] bf16
// ---------------------------------------------------------------------------
__global__ __launch_bounds__(256)
void prep_kernel(const float* __restrict__ wqkv, const float* __restrict__ wmerge,
                 const float* __restrict__ w1, const float* __restrict__ w2,
                 const float* __restrict__ btab, const int* __restrict__ relidx,
                 bf16* __restrict__ wqkvT, bf16* __restrict__ wmergeT,
                 bf16* __restrict__ w1T, bf16* __restrict__ w2T,
                 short* __restrict__ bt)
{
  int idx = blockIdx.x * 256 + threadIdx.x;
  if (idx < 196608) { int n = idx >> 8, k = idx & 255;
    wqkvT[idx] = __float2bfloat16(wqkv[k * 768 + n]); return; }
  idx -= 196608;
  if (idx < 65536) { int n = idx >> 8, k = idx & 255;
    wmergeT[idx] = __float2bfloat16(wmerge[k * 256 + n]); return; }
  idx -= 65536;
  if (idx < 262144) { int n = idx >> 8, k = idx & 255;
    w1T[idx] = __float2bfloat16(w1[k * 1024 + n]); return; }
  idx -= 262144;
  if (idx < 262144) { int n = idx >> 10, k = idx & 1023;
    w2T[idx] = __float2bfloat16(w2[k * 256 + n]); return; }
  idx -= 262144;
  if (idx < 32768) {
    int h = idx >> 12, rest = idx & 4095;
    int key = rest >> 6, col = rest & 63;
    int q = col >> 2, qni = col & 3;
    int query = qni * 16 + q;
    float v = 0.f;
    if (key < P_ && query < P_) v = btab[relidx[query * P_ + key] * HEADS_ + h];
    bt[idx] = f2b(v);
  }
}

// ---------------------------------------------------------------------------
// ingest: coalesced BCHW read -> LN1 -> y bf16 [NTOK][256], xtok bf16 [NTOK][256]
// block = (b,h); thread (w=tid&63, cblk=tid>>6) owns token(w), channels cblk*64..+63
// ---------------------------------------------------------------------------
__global__ __launch_bounds__(256)
void ingest_kernel(const float* __restrict__ x, const float* __restrict__ gam,
                   const float* __restrict__ bet, short* __restrict__ xtok,
                   short* __restrict__ y)
{
  __shared__ float red[2][4][64];
  const int h = blockIdx.x % 56, b = blockIdx.x / 56;
  const int w = threadIdx.x & 63, cblk = threadIdx.x >> 6;
  const bool act = w < 56;
  const int wcl = act ? w : 55;

  const float* xb = x + ((size_t)b * 256 + cblk * 64) * HW_ + h * 56 + wcl;
  float v[64];
  float sum = 0.f, sq = 0.f;
#pragma unroll
  for (int j = 0; j < 64; j++) {
    float t = xb[(size_t)j * HW_];
    v[j] = t; sum += t; sq += t * t;
  }
  red[0][cblk][w] = sum; red[1][cblk][w] = sq;
  __syncthreads();
  sum = red[0][0][w] + red[0][1][w] + red[0][2][w] + red[0][3][w];
  sq  = red[1][0][w] + red[1][1][w] + red[1][2][w] + red[1][3][w];
  float mu = sum * (1.0f / 256.0f);
  float var = sq * (1.0f / 256.0f) - mu * mu;
  float rs = rsqrtf(var + EPS_);

  if (!act) return;
  const int tok = b * HW_ + ((h / 7) * 8 + w / 7) * P_ + (h % 7) * 7 + (w % 7);
  short* yp = y    + (size_t)tok * 256 + cblk * 64;
  short* xp = xtok + (size_t)tok * 256 + cblk * 64;
#pragma unroll
  for (int j0 = 0; j0 < 64; j0 += 8) {
    bf16x8 py, px;
#pragma unroll
    for (int jj = 0; jj < 8; jj++) {
      int j = j0 + jj, c = cblk * 64 + j;
      px[jj] = f2b(v[j]);
      py[jj] = f2b((v[j] - mu) * rs * gam[c] + bet[c]);
    }
    *(bf16x8*)(yp + j0) = py;
    *(bf16x8*)(xp + j0) = px;
  }
}

// ---------------------------------------------------------------------------
// ln2: xw (bf16 token-major) -> z bf16. wave per token, lane = 4 channels.
// ---------------------------------------------------------------------------
__global__ __launch_bounds__(256)
void ln2_kernel(const short* __restrict__ xw, const float* __restrict__ gam,
                const float* __restrict__ bet, short* __restrict__ z)
{
  const int t = blockIdx.x * 4 + (threadIdx.x >> 6);
  const int lane = threadIdx.x & 63;
  bf16x4_t raw = *(const bf16x4_t*)(xw + (size_t)t * 256 + lane * 4);
  float v[4];
#pragma unroll
  for (int j = 0; j < 4; j++) v[j] = b2f(raw[j]);
  float sum = v[0] + v[1] + v[2] + v[3];
  float sq  = v[0]*v[0] + v[1]*v[1] + v[2]*v[2] + v[3]*v[3];
#pragma unroll
  for (int off = 32; off > 0; off >>= 1) {
    sum += __shfl_xor(sum, off, 64);
    sq  += __shfl_xor(sq,  off, 64);
  }
  float mu = sum * (1.0f / 256.0f);
  float var = sq * (1.0f / 256.0f) - mu * mu;
  float rs = rsqrtf(var + EPS_);
  bf16x4_t o;
#pragma unroll
  for (int j = 0; j < 4; j++) {
    int c = lane * 4 + j;
    o[j] = f2b((v[j] - mu) * rs * gam[c] + bet[c]);
  }
  *(bf16x4_t*)(z + (size_t)t * 256 + lane * 4) = o;
}

// ---------------------------------------------------------------------------
// egress: token-major bf16 -> BCHW f32 out (coalesced both sides)
// ---------------------------------------------------------------------------
__global__ __launch_bounds__(256)
void egress_kernel(const short* __restrict__ outtok, float* __restrict__ out)
{
  const int h = blockIdx.x % 56, b = blockIdx.x / 56;
  const int w = threadIdx.x & 63, cblk = threadIdx.x >> 6;
  const bool act = w < 56;
  const int wcl = act ? w : 55;
  const int tok = b * HW_ + ((h / 7) * 8 + wcl / 7) * P_ + (h % 7) * 7 + (wcl % 7);
  const short* src = outtok + (size_t)tok * 256 + cblk * 64;
  float* dst = out + ((size_t)b * 256 + cblk * 64) * HW_ + h * 56 + w;
#pragma unroll
  for (int j0 = 0; j0 < 64; j0 += 8) {
    bf16x8 r = *(const bf16x8*)(src + j0);
#pragma unroll
    for (int jj = 0; jj < 8; jj++)
      if (act) dst[(size_t)(j0 + jj) * HW_] = b2f(r[jj]);
  }
}

// ---------------------------------------------------------------------------
// attention (MFMA): one wave per (window, head), chunk-local pointers
// ---------------------------------------------------------------------------
__global__ __launch_bounds__(64)
void attn_kernel(const short* __restrict__ qkv, const short* __restrict__ bt,
                 short* __restrict__ out)
{
  __shared__ short Pbuf[64 * 72];
  const int bid = blockIdx.x;
  const int h = bid & 7;
  const int t0 = (bid >> 3) * P_;
  const int lane = threadIdx.x;
  const int g = lane >> 4, q = lane & 15;

  const short* qb = qkv + (size_t)t0 * 768 + h * 32;

  bf16x8 vf[2][2];
#pragma unroll
  for (int kkt = 0; kkt < 2; kkt++)
#pragma unroll
    for (int n2 = 0; n2 < 2; n2++)
#pragma unroll
      for (int jj = 0; jj < 8; jj++) {
        int key = kkt * 32 + 8 * g + jj; key = key > 48 ? 48 : key;
        vf[kkt][n2][jj] = qb[(size_t)key * 768 + 512 + n2 * 16 + q];
      }

  bf16x8 kf[4], qf[4];
#pragma unroll
  for (int mi = 0; mi < 4; mi++) {
    int r_ = mi * 16 + q; r_ = r_ > 48 ? 48 : r_;
    kf[mi] = *(const bf16x8*)(qb + (size_t)r_ * 768 + 256 + 8 * g);
  }
#pragma unroll
  for (int ni = 0; ni < 4; ni++) {
    int r_ = ni * 16 + q; r_ = r_ > 48 ? 48 : r_;
    qf[ni] = *(const bf16x8*)(qb + (size_t)r_ * 768 + 8 * g);
  }

  f32x4 sacc[4][4] = {};
#pragma unroll
  for (int mi = 0; mi < 4; mi++)
#pragma unroll
    for (int ni = 0; ni < 4; ni++)
      sacc[mi][ni] = __builtin_amdgcn_mfma_f32_16x16x32_bf16(kf[mi], qf[ni], sacc[mi][ni], 0, 0, 0);

  float mx[4] = {-1e30f, -1e30f, -1e30f, -1e30f};
  const short* btb = bt + (size_t)(h * 64) * 64 + q * 4;
#pragma unroll
  for (int mi = 0; mi < 4; mi++)
#pragma unroll
    for (int r = 0; r < 4; r++) {
      int key = mi * 16 + 4 * g + r;
      bf16x4_t bv = *(const bf16x4_t*)(btb + key * 64);
      bool valid = key < P_;
#pragma unroll
      for (int ni = 0; ni < 4; ni++) {
        float s = valid ? fmaf(sacc[mi][ni][r], SCALE_, b2f(bv[ni])) : -1e30f;
        sacc[mi][ni][r] = s;
        mx[ni] = fmaxf(mx[ni], s);
      }
    }
#pragma unroll
  for (int ni = 0; ni < 4; ni++) {
    mx[ni] = fmaxf(mx[ni], __shfl_xor(mx[ni], 16, 64));
    mx[ni] = fmaxf(mx[ni], __shfl_xor(mx[ni], 32, 64));
  }
  float sm[4] = {0.f, 0.f, 0.f, 0.f};
#pragma unroll
  for (int mi = 0; mi < 4; mi++)
#pragma unroll
    for (int ni = 0; ni < 4; ni++)
#pragma unroll
      for (int r = 0; r < 4; r++) {
        float p = __expf(sacc[mi][ni][r] - mx[ni]);
        sacc[mi][ni][r] = p;
        sm[ni] += p;
      }
#pragma unroll
  for (int ni = 0; ni < 4; ni++) {
    sm[ni] += __shfl_xor(sm[ni], 16, 64);
    sm[ni] += __shfl_xor(sm[ni], 32, 64);
    sm[ni] = 1.0f / sm[ni];
  }
#pragma unroll
  for (int ni = 0; ni < 4; ni++)
#pragma unroll
    for (int mi = 0; mi < 4; mi++) {
      bf16x4_t pv;
#pragma unroll
      for (int r = 0; r < 4; r++) pv[r] = f2b(sacc[mi][ni][r] * sm[ni]);
      *(bf16x4_t*)&Pbuf[(ni * 16 + q) * 72 + mi * 16 + 4 * g] = pv;
    }
  __syncthreads();

  f32x4 oacc[4][2] = {};
#pragma unroll
  for (int kkt = 0; kkt < 2; kkt++) {
    bf16x8 paf[4];
#pragma unroll
    for (int qi = 0; qi < 4; qi++)
      paf[qi] = *(const bf16x8*)&Pbuf[(qi * 16 + q) * 72 + kkt * 32 + 8 * g];
#pragma unroll
    for (int qi = 0; qi < 4; qi++)
#pragma unroll
      for (int n2 = 0; n2 < 2; n2++)
        oacc[qi][n2] = __builtin_amdgcn_mfma_f32_16x16x32_bf16(paf[qi], vf[kkt][n2], oacc[qi][n2], 0, 0, 0);
  }

  short* ob = out + (size_t)t0 * 256 + h * 32;
#pragma unroll
  for (int qi = 0; qi < 4; qi++)
#pragma unroll
    for (int r = 0; r < 4; r++) {
      int query = qi * 16 + 4 * g + r;
      if (query < P_) {
#pragma unroll
        for (int n2 = 0; n2 < 2; n2++)
          ob[(size_t)query * 256 + n2 * 16 + q] = f2b(oacc[qi][n2][r]);
      }
    }
}

// ---------------------------------------------------------------------------
// GEMM 128x256 tile, 512 threads (8 waves 2x4), 16x16x32 MFMA, gload_lds.
// EPI 0: bf16 store   EPI 1: gelu -> bf16   EPI 2: in-place residual add on res_io
// ---------------------------------------------------------------------------
template<int EPI>
__global__ __launch_bounds__(512)
void gemm_kernel(const bf16* __restrict__ A, const bf16* __restrict__ Wt,
                 const float* __restrict__ bias, int N, int K,
                 bf16* __restrict__ outb, short* __restrict__ res_io)
{
  __shared__ __align__(16) bf16 As[128 * 32];
  __shared__ __align__(16) bf16 Bs[256 * 32];
  const int tid = threadIdx.x;
  const int lane = tid & 63;
  const int wave = tid >> 6;
  const int wr = wave >> 2, wc = wave & 3;
  const int bm = blockIdx.y * 128, bn = blockIdx.x * 256;

  f32x4 acc[4][4] = {};

  const int trow = tid >> 2;
  const int tcol = (tid & 3) * 8;
  const bf16* aA  = A  + (size_t)(bm + trow) * K + tcol;
  const bf16* aB0 = Wt + (size_t)(bn + trow) * K + tcol;
  const bf16* aB1 = Wt + (size_t)(bn + 128 + trow) * K + tcol;
  bf16* dA  = As + tid * 8;
  bf16* dB0 = Bs + tid * 8;
  bf16* dB1 = Bs + 4096 + tid * 8;

  const int kc16 = (lane >> 4) * 8;
  const int rA = wr * 64 + (lane & 15);
  const int rB = wc * 64 + (lane & 15);

  for (int k0 = 0; k0 < K; k0 += 32) {
    gload16(aA + k0, dA);
    gload16(aB0 + k0, dB0);
    gload16(aB1 + k0, dB1);
    __syncthreads();
    bf16x8 af[4], bfr[4];
#pragma unroll
    for (int i = 0; i < 4; i++) {
      af[i]  = *(const bf16x8*)(As + (rA + i * 16) * 32 + kc16);
      bfr[i] = *(const bf16x8*)(Bs + (rB + i * 16) * 32 + kc16);
    }
#pragma unroll
    for (int mi = 0; mi < 4; mi++)
#pragma unroll
      for (int ni = 0; ni < 4; ni++)
        acc[mi][ni] = __builtin_amdgcn_mfma_f32_16x16x32_bf16(af[mi], bfr[ni], acc[mi][ni], 0, 0, 0);
    __syncthreads();
  }

#pragma unroll
  for (int mi = 0; mi < 4; mi++) {
#pragma unroll
    for (int ni = 0; ni < 4; ni++) {
#pragma unroll
      for (int r = 0; r < 4; r++) {
        const int row = bm + wr * 64 + mi * 16 + (lane >> 4) * 4 + r;
        const int col = bn + wc * 64 + ni * 16 + (lane & 15);
        float v = acc[mi][ni][r] + bias[col];
        if (EPI == 0) {
          outb[(size_t)row * N + col] = __float2bfloat16(v);
        } else if (EPI == 1) {
          float gv = 0.5f * v * (1.0f + erff(v * 0.70710678118f));
          outb[(size_t)row * N + col] = __float2bfloat16(gv);
        } else {
          size_t o = (size_t)row * 256 + col;
          res_io[o] = f2b(v + b2f(res_io[o]));
        }
      }
    }
  }
}

// ---------------------------------------------------------------------------
extern "C" void kernel_launch(void* const* d_in, const int* in_sizes, int n_in,
                              void* d_out, int out_size, void* d_ws, size_t ws_size,
                              hipStream_t stream)
{
  const float* x      = (const float*)d_in[0];
  const float* ln1_g  = (const float*)d_in[1];
  const float* ln1_b  = (const float*)d_in[2];
  const float* wqkv   = (const float*)d_in[3];
  const float* bqkv   = (const float*)d_in[4];
  const float* wmerge = (const float*)d_in[5];
  const float* bmerge = (const float*)d_in[6];
  const float* btab   = (const float*)d_in[7];
  const float* ln2_g  = (const float*)d_in[8];
  const float* ln2_b  = (const float*)d_in[9];
  const float* w1     = (const float*)d_in[10];
  const float* b1     = (const float*)d_in[11];
  const float* w2     = (const float*)d_in[12];
  const float* b2     = (const float*)d_in[13];
  const int*   relidx = (const int*)d_in[14];
  float* out = (float*)d_out;

  char* ws = (char*)d_ws;
  // weights region: 1,638,400 B
  bf16*  wqkvT   = (bf16*)(ws);
  bf16*  wmergeT = (bf16*)(ws + 393216);
  bf16*  w1T     = (bf16*)(ws + 524288);
  bf16*  w2T     = (bf16*)(ws + 1048576);
  short* battn   = (short*)(ws + 1572864);
  // R1: residual stream xtok -> xw -> out (in-place), bf16 [NTOK][256]
  short* R1      = (short*)(ws + 1638400);        // 25,690,112
  // R2: y / z bf16 [NTOK][256]
  short* R2      = (short*)(ws + 27328512);       // 25,690,112
  // R3: per-chunk qkv (19,267,584) + attn-out (6,422,528); hbuf aliases all
  short* qkvc    = (short*)(ws + 53018624);
  short* attnc   = (short*)(ws + 72286208);
  short* hbuf    = (short*)(ws + 53018624);       // aliases qkvc+attnc (dead by MLP)
  // end: 78,708,736

  prep_kernel<<<3200, 256, 0, stream>>>(wqkv, wmerge, w1, w2, btab, relidx,
                                        wqkvT, wmergeT, w1T, w2T, battn);

  ingest_kernel<<<896, 256, 0, stream>>>(x, ln1_g, ln1_b, R1, R2);

  // attention path, 4 window-aligned chunks of 12544 tokens
  for (int c = 0; c < 4; ++c) {
    size_t r0 = (size_t)c * 12544;
    gemm_kernel<0><<<dim3(3, 98), 512, 0, stream>>>(
        (const bf16*)(R2 + r0 * 256), wqkvT, bqkv, 768, 256, (bf16*)qkvc, nullptr);
    attn_kernel<<<2048, 64, 0, stream>>>(qkvc, battn, attnc);
    gemm_kernel<2><<<dim3(1, 98), 512, 0, stream>>>(
        (const bf16*)attnc, wmergeT, bmerge, 256, 256, nullptr, R1 + r0 * 256);
  }

  // LN2 over full xw -> z
  ln2_kernel<<<NTOK / 4, 256, 0, stream>>>(R1, ln2_g, ln2_b, R2);

  // MLP, 4 chunks
  for (int c = 0; c < 4; ++c) {
    size_t r0 = (size_t)c * 12544;
    gemm_kernel<1><<<dim3(4, 98), 512, 0, stream>>>(
        (const bf16*)(R2 + r0 * 256), w1T, b1, 1024, 256, (bf16*)hbuf, nullptr);
    gemm_kernel<2><<<dim3(1, 98), 512, 0, stream>>>(
        (const bf16*)hbuf, w2T, b2, 256, 1024, nullptr, R1 + r0 * 256);
  }

  egress_kernel<<<896, 256, 0, stream>>>(R1, out);
}

// Round 4
// 291.285 us; speedup vs baseline: 1.9442x; 1.4528x over previous
//
#include <hip/hip_runtime.h>
#include <hip/hip_bf16.h>

#define B_      16
#define C_      256
#define H_      56
#define W_      56
#define HW_     3136
#define G_      64
#define P_      49
#define NTOK    50176
#define HEADS_  8
#define DH_     32
#define SCALE_  0.0625f
#define EPS_    1e-5f

typedef short bf16x8 __attribute__((ext_vector_type(8)));
typedef short bf16x4_t __attribute__((ext_vector_type(4)));
typedef float f32x4  __attribute__((ext_vector_type(4)));
using bf16 = __hip_bfloat16;

__device__ __forceinline__ void gload16(const void* g, void* l) {
  __builtin_amdgcn_global_load_lds((const __attribute__((address_space(1))) void*)g,
                                   (__attribute__((address_space(3))) void*)l, 16, 0, 0);
}
__device__ __forceinline__ float b2f(short s) {
  union { float f; unsigned u; } v; v.u = ((unsigned)(unsigned short)s) << 16; return v.f;
}
__device__ __forceinline__ short f2b(float f) {   // RNE
  union { float f; unsigned u; } v; v.f = f;
  unsigned r = (v.u + 0x7FFFu + ((v.u >> 16) & 1u)) >> 16;
  return (short)r;
}

// ---------------------------------------------------------------------------
// prep: weights -> [N][K] bf16; bias -> bt[h][key(64)][q*4+qni] bf16
// ---------------------------------------------------------------------------
__global__ __launch_bounds__(256)
void prep_kernel(const float* __restrict__ wqkv, const float* __restrict__ wmerge,
                 const float* __restrict__ w1, const float* __restrict__ w2,
                 const float* __restrict__ btab, const int* __restrict__ relidx,
                 bf16* __restrict__ wqkvT, bf16* __restrict__ wmergeT,
                 bf16* __restrict__ w1T, bf16* __restrict__ w2T,
                 short* __restrict__ bt)
{
  int idx = blockIdx.x * 256 + threadIdx.x;
  if (idx < 196608) { int n = idx >> 8, k = idx & 255;
    wqkvT[idx] = __float2bfloat16(wqkv[k * 768 + n]); return; }
  idx -= 196608;
  if (idx < 65536) { int n = idx >> 8, k = idx & 255;
    wmergeT[idx] = __float2bfloat16(wmerge[k * 256 + n]); return; }
  idx -= 65536;
  if (idx < 262144) { int n = idx >> 8, k = idx & 255;
    w1T[idx] = __float2bfloat16(w1[k * 1024 + n]); return; }
  idx -= 262144;
  if (idx < 262144) { int n = idx >> 10, k = idx & 1023;
    w2T[idx] = __float2bfloat16(w2[k * 256 + n]); return; }
  idx -= 262144;
  if (idx < 32768) {
    int h = idx >> 12, rest = idx & 4095;
    int key = rest >> 6, col = rest & 63;
    int q = col >> 2, qni = col & 3;
    int query = qni * 16 + q;
    float v = 0.f;
    if (key < P_ && query < P_) v = btab[relidx[query * P_ + key] * HEADS_ + h];
    bt[idx] = f2b(v);
  }
}

// ---------------------------------------------------------------------------
// ingest: block=(b,h). Phase1: float4-coalesced read of x[b][:][h][:],
// bf16 into LDS [56][260] transposed. Phase2: wave-per-token LN, contiguous
// 512B row writes of xtok (raw) and y (normalized).
// ---------------------------------------------------------------------------
__global__ __launch_bounds__(256)
void ingest_kernel(const float* __restrict__ x, const float* __restrict__ gam,
                   const float* __restrict__ bet, short* __restrict__ xtok,
                   short* __restrict__ y)
{
  __shared__ short Lt[56 * 260];
  const int h = blockIdx.x % 56, b = blockIdx.x / 56;
  const int tid = threadIdx.x;

  const float* xb = x + (size_t)b * 256 * HW_ + h * 56;
#pragma unroll
  for (int i = 0; i < 14; i++) {
    int idx = i * 256 + tid;
    int c = idx / 14, w4 = idx - c * 14;
    float4 v = *(const float4*)(xb + (size_t)c * HW_ + w4 * 4);
    Lt[(w4 * 4 + 0) * 260 + c] = f2b(v.x);
    Lt[(w4 * 4 + 1) * 260 + c] = f2b(v.y);
    Lt[(w4 * 4 + 2) * 260 + c] = f2b(v.z);
    Lt[(w4 * 4 + 3) * 260 + c] = f2b(v.w);
  }
  __syncthreads();

  const int lane = tid & 63, wv = tid >> 6;
  float4 gv = *(const float4*)(gam + lane * 4);
  float4 bv = *(const float4*)(bet + lane * 4);
  const int hdiv = h / 7, hmod = h - hdiv * 7;

  for (int t = 0; t < 14; t++) {
    int w = wv * 14 + t;
    bf16x4_t raw = *(const bf16x4_t*)&Lt[w * 260 + lane * 4];
    float f0 = b2f(raw[0]), f1 = b2f(raw[1]), f2 = b2f(raw[2]), f3 = b2f(raw[3]);
    float sum = f0 + f1 + f2 + f3;
    float sq  = f0*f0 + f1*f1 + f2*f2 + f3*f3;
#pragma unroll
    for (int off = 32; off > 0; off >>= 1) {
      sum += __shfl_xor(sum, off, 64);
      sq  += __shfl_xor(sq,  off, 64);
    }
    float mu = sum * (1.0f / 256.0f);
    float var = sq * (1.0f / 256.0f) - mu * mu;
    float rs = rsqrtf(var + EPS_);
    int wdiv = w / 7, wmod = w - wdiv * 7;
    int tok = b * HW_ + (hdiv * 8 + wdiv) * P_ + hmod * 7 + wmod;
    *(bf16x4_t*)(xtok + (size_t)tok * 256 + lane * 4) = raw;
    bf16x4_t o;
    o[0] = f2b((f0 - mu) * rs * gv.x + bv.x);
    o[1] = f2b((f1 - mu) * rs * gv.y + bv.y);
    o[2] = f2b((f2 - mu) * rs * gv.z + bv.z);
    o[3] = f2b((f3 - mu) * rs * gv.w + bv.w);
    *(bf16x4_t*)(y + (size_t)tok * 256 + lane * 4) = o;
  }
}

// ---------------------------------------------------------------------------
// ln2: xw (bf16 token-major) -> z bf16. wave per token.
// ---------------------------------------------------------------------------
__global__ __launch_bounds__(256)
void ln2_kernel(const short* __restrict__ xw, const float* __restrict__ gam,
                const float* __restrict__ bet, short* __restrict__ z)
{
  const int t = blockIdx.x * 4 + (threadIdx.x >> 6);
  const int lane = threadIdx.x & 63;
  bf16x4_t raw = *(const bf16x4_t*)(xw + (size_t)t * 256 + lane * 4);
  float v[4];
#pragma unroll
  for (int j = 0; j < 4; j++) v[j] = b2f(raw[j]);
  float sum = v[0] + v[1] + v[2] + v[3];
  float sq  = v[0]*v[0] + v[1]*v[1] + v[2]*v[2] + v[3]*v[3];
#pragma unroll
  for (int off = 32; off > 0; off >>= 1) {
    sum += __shfl_xor(sum, off, 64);
    sq  += __shfl_xor(sq,  off, 64);
  }
  float mu = sum * (1.0f / 256.0f);
  float var = sq * (1.0f / 256.0f) - mu * mu;
  float rs = rsqrtf(var + EPS_);
  bf16x4_t o;
#pragma unroll
  for (int j = 0; j < 4; j++) {
    int c = lane * 4 + j;
    o[j] = f2b((v[j] - mu) * rs * gam[c] + bet[c]);
  }
  *(bf16x4_t*)(z + (size_t)t * 256 + lane * 4) = o;
}

// ---------------------------------------------------------------------------
// egress: token-major bf16 -> BCHW f32 out
// ---------------------------------------------------------------------------
__global__ __launch_bounds__(256)
void egress_kernel(const short* __restrict__ outtok, float* __restrict__ out)
{
  const int h = blockIdx.x % 56, b = blockIdx.x / 56;
  const int w = threadIdx.x & 63, cblk = threadIdx.x >> 6;
  const bool act = w < 56;
  const int wcl = act ? w : 55;
  const int tok = b * HW_ + ((h / 7) * 8 + wcl / 7) * P_ + (h % 7) * 7 + (wcl % 7);
  const short* src = outtok + (size_t)tok * 256 + cblk * 64;
  float* dst = out + ((size_t)b * 256 + cblk * 64) * HW_ + h * 56 + w;
#pragma unroll
  for (int j0 = 0; j0 < 64; j0 += 8) {
    bf16x8 r = *(const bf16x8*)(src + j0);
#pragma unroll
    for (int jj = 0; jj < 8; jj++)
      if (act) dst[(size_t)(j0 + jj) * HW_] = b2f(r[jj]);
  }
}

// ---------------------------------------------------------------------------
// attention (MFMA): one wave per (window, head), chunk-local pointers
// ---------------------------------------------------------------------------
__global__ __launch_bounds__(64)
void attn_kernel(const short* __restrict__ qkv, const short* __restrict__ bt,
                 short* __restrict__ out)
{
  __shared__ short Pbuf[64 * 72];
  const int bid = blockIdx.x;
  const int h = bid & 7;
  const int t0 = (bid >> 3) * P_;
  const int lane = threadIdx.x;
  const int g = lane >> 4, q = lane & 15;

  const short* qb = qkv + (size_t)t0 * 768 + h * 32;

  bf16x8 vf[2][2];
#pragma unroll
  for (int kkt = 0; kkt < 2; kkt++)
#pragma unroll
    for (int n2 = 0; n2 < 2; n2++)
#pragma unroll
      for (int jj = 0; jj < 8; jj++) {
        int key = kkt * 32 + 8 * g + jj; key = key > 48 ? 48 : key;
        vf[kkt][n2][jj] = qb[(size_t)key * 768 + 512 + n2 * 16 + q];
      }

  bf16x8 kf[4], qf[4];
#pragma unroll
  for (int mi = 0; mi < 4; mi++) {
    int r_ = mi * 16 + q; r_ = r_ > 48 ? 48 : r_;
    kf[mi] = *(const bf16x8*)(qb + (size_t)r_ * 768 + 256 + 8 * g);
  }
#pragma unroll
  for (int ni = 0; ni < 4; ni++) {
    int r_ = ni * 16 + q; r_ = r_ > 48 ? 48 : r_;
    qf[ni] = *(const bf16x8*)(qb + (size_t)r_ * 768 + 8 * g);
  }

  f32x4 sacc[4][4] = {};
#pragma unroll
  for (int mi = 0; mi < 4; mi++)
#pragma unroll
    for (int ni = 0; ni < 4; ni++)
      sacc[mi][ni] = __builtin_amdgcn_mfma_f32_16x16x32_bf16(kf[mi], qf[ni], sacc[mi][ni], 0, 0, 0);

  float mx[4] = {-1e30f, -1e30f, -1e30f, -1e30f};
  const short* btb = bt + (size_t)(h * 64) * 64 + q * 4;
#pragma unroll
  for (int mi = 0; mi < 4; mi++)
#pragma unroll
    for (int r = 0; r < 4; r++) {
      int key = mi * 16 + 4 * g + r;
      bf16x4_t bv = *(const bf16x4_t*)(btb + key * 64);
      bool valid = key < P_;
#pragma unroll
      for (int ni = 0; ni < 4; ni++) {
        float s = valid ? fmaf(sacc[mi][ni][r], SCALE_, b2f(bv[ni])) : -1e30f;
        sacc[mi][ni][r] = s;
        mx[ni] = fmaxf(mx[ni], s);
      }
    }
#pragma unroll
  for (int ni = 0; ni < 4; ni++) {
    mx[ni] = fmaxf(mx[ni], __shfl_xor(mx[ni], 16, 64));
    mx[ni] = fmaxf(mx[ni], __shfl_xor(mx[ni], 32, 64));
  }
  float sm[4] = {0.f, 0.f, 0.f, 0.f};
#pragma unroll
  for (int mi = 0; mi < 4; mi++)
#pragma unroll
    for (int ni = 0; ni < 4; ni++)
#pragma unroll
      for (int r = 0; r < 4; r++) {
        float p = __expf(sacc[mi][ni][r] - mx[ni]);
        sacc[mi][ni][r] = p;
        sm[ni] += p;
      }
#pragma unroll
  for (int ni = 0; ni < 4; ni++) {
    sm[ni] += __shfl_xor(sm[ni], 16, 64);
    sm[ni] += __shfl_xor(sm[ni], 32, 64);
    sm[ni] = 1.0f / sm[ni];
  }
#pragma unroll
  for (int ni = 0; ni < 4; ni++)
#pragma unroll
    for (int mi = 0; mi < 4; mi++) {
      bf16x4_t pv;
#pragma unroll
      for (int r = 0; r < 4; r++) pv[r] = f2b(sacc[mi][ni][r] * sm[ni]);
      *(bf16x4_t*)&Pbuf[(ni * 16 + q) * 72 + mi * 16 + 4 * g] = pv;
    }
  __syncthreads();

  f32x4 oacc[4][2] = {};
#pragma unroll
  for (int kkt = 0; kkt < 2; kkt++) {
    bf16x8 paf[4];
#pragma unroll
    for (int qi = 0; qi < 4; qi++)
      paf[qi] = *(const bf16x8*)&Pbuf[(qi * 16 + q) * 72 + kkt * 32 + 8 * g];
#pragma unroll
    for (int qi = 0; qi < 4; qi++)
#pragma unroll
      for (int n2 = 0; n2 < 2; n2++)
        oacc[qi][n2] = __builtin_amdgcn_mfma_f32_16x16x32_bf16(paf[qi], vf[kkt][n2], oacc[qi][n2], 0, 0, 0);
  }

  short* ob = out + (size_t)t0 * 256 + h * 32;
#pragma unroll
  for (int qi = 0; qi < 4; qi++)
#pragma unroll
    for (int r = 0; r < 4; r++) {
      int query = qi * 16 + 4 * g + r;
      if (query < P_) {
#pragma unroll
        for (int n2 = 0; n2 < 2; n2++)
          ob[(size_t)query * 256 + n2 * 16 + q] = f2b(oacc[qi][n2][r]);
      }
    }
}

// ---------------------------------------------------------------------------
// GEMM: BM=128, BN=64*WN, threads=128*WN (WN=2 or 4), 16x16x32 MFMA,
// gload_lds staging with XOR-swizzled source cols + swizzled ds_reads (T2).
// EPI 0: bf16 store   EPI 1: gelu -> bf16   EPI 2: in-place residual add
// ---------------------------------------------------------------------------
template<int EPI, int WN>
__global__ __launch_bounds__(128 * WN)
void gemm_kernel(const bf16* __restrict__ A, const bf16* __restrict__ Wt,
                 const float* __restrict__ bias, int N, int K,
                 bf16* __restrict__ outb, short* __restrict__ res_io)
{
  constexpr int THREADS = 128 * WN;
  constexpr int BN = 64 * WN;
  constexpr int RPP = THREADS / 4;      // rows staged per pass
  constexpr int APASS = 128 / RPP;      // 2 (WN=2) or 1 (WN=4)
  __shared__ __align__(16) bf16 As[128 * 32];
  __shared__ __align__(16) bf16 Bs[BN * 32];
  const int tid = threadIdx.x;
  const int lane = tid & 63;
  const int wave = tid >> 6;
  const int wr = wave / WN, wc = wave % WN;
  const int bm = blockIdx.y * 128, bn = blockIdx.x * BN;

  f32x4 acc[4][4] = {};

  const int trow = tid >> 2;
  const int tcol = ((tid & 3) ^ ((tid >> 3) & 3)) * 8;   // swizzled source chunk
  const bf16* aA[APASS];
  bf16* dA[APASS];
#pragma unroll
  for (int p = 0; p < APASS; p++) {
    aA[p] = A + (size_t)(bm + p * RPP + trow) * K + tcol;
    dA[p] = As + p * RPP * 32 + tid * 8;
  }
  const bf16* aB0 = Wt + (size_t)(bn + trow) * K + tcol;
  const bf16* aB1 = Wt + (size_t)(bn + RPP + trow) * K + tcol;
  bf16* dB0 = Bs + tid * 8;
  bf16* dB1 = Bs + RPP * 32 + tid * 8;

  const int kc_sw = ((lane >> 4) ^ ((lane >> 1) & 3)) * 8;  // swizzled read chunk
  const int rA = wr * 64 + (lane & 15);
  const int rB = wc * 64 + (lane & 15);

  for (int k0 = 0; k0 < K; k0 += 32) {
#pragma unroll
    for (int p = 0; p < APASS; p++) gload16(aA[p] + k0, dA[p]);
    gload16(aB0 + k0, dB0);
    gload16(aB1 + k0, dB1);
    __syncthreads();
    bf16x8 af[4], bfr[4];
#pragma unroll
    for (int i = 0; i < 4; i++) {
      af[i]  = *(const bf16x8*)(As + (rA + i * 16) * 32 + kc_sw);
      bfr[i] = *(const bf16x8*)(Bs + (rB + i * 16) * 32 + kc_sw);
    }
#pragma unroll
    for (int mi = 0; mi < 4; mi++)
#pragma unroll
      for (int ni = 0; ni < 4; ni++)
        acc[mi][ni] = __builtin_amdgcn_mfma_f32_16x16x32_bf16(af[mi], bfr[ni], acc[mi][ni], 0, 0, 0);
    __syncthreads();
  }

#pragma unroll
  for (int mi = 0; mi < 4; mi++) {
#pragma unroll
    for (int ni = 0; ni < 4; ni++) {
#pragma unroll
      for (int r = 0; r < 4; r++) {
        const int row = bm + wr * 64 + mi * 16 + (lane >> 4) * 4 + r;
        const int col = bn + wc * 64 + ni * 16 + (lane & 15);
        float v = acc[mi][ni][r] + bias[col];
        if (EPI == 0) {
          outb[(size_t)row * N + col] = __float2bfloat16(v);
        } else if (EPI == 1) {
          float gv = 0.5f * v * (1.0f + erff(v * 0.70710678118f));
          outb[(size_t)row * N + col] = __float2bfloat16(gv);
        } else {
          size_t o = (size_t)row * 256 + col;
          res_io[o] = f2b(v + b2f(res_io[o]));
        }
      }
    }
  }
}

// ---------------------------------------------------------------------------
extern "C" void kernel_launch(void* const* d_in, const int* in_sizes, int n_in,
                              void* d_out, int out_size, void* d_ws, size_t ws_size,
                              hipStream_t stream)
{
  const float* x      = (const float*)d_in[0];
  const float* ln1_g  = (const float*)d_in[1];
  const float* ln1_b  = (const float*)d_in[2];
  const float* wqkv   = (const float*)d_in[3];
  const float* bqkv   = (const float*)d_in[4];
  const float* wmerge = (const float*)d_in[5];
  const float* bmerge = (const float*)d_in[6];
  const float* btab   = (const float*)d_in[7];
  const float* ln2_g  = (const float*)d_in[8];
  const float* ln2_b  = (const float*)d_in[9];
  const float* w1     = (const float*)d_in[10];
  const float* b1     = (const float*)d_in[11];
  const float* w2     = (const float*)d_in[12];
  const float* b2     = (const float*)d_in[13];
  const int*   relidx = (const int*)d_in[14];
  float* out = (float*)d_out;

  char* ws = (char*)d_ws;
  bf16*  wqkvT   = (bf16*)(ws);                   // 393,216
  bf16*  wmergeT = (bf16*)(ws + 393216);          // 131,072
  bf16*  w1T     = (bf16*)(ws + 524288);          // 524,288
  bf16*  w2T     = (bf16*)(ws + 1048576);         // 524,288
  short* battn   = (short*)(ws + 1572864);        // 65,536
  short* R1      = (short*)(ws + 1638400);        // 25,690,112 residual stream
  short* R2      = (short*)(ws + 27328512);       // 25,690,112 y / z
  short* qkvc    = (short*)(ws + 53018624);       // 38,535,168 (half-chunk qkv)
  short* attnc   = (short*)(ws + 91553792);       // 12,845,056
  short* hbuf    = (short*)(ws + 53018624);       // 51,380,224 (aliases qkvc+attnc)
  // end: 104,398,848

  prep_kernel<<<3200, 256, 0, stream>>>(wqkv, wmerge, w1, w2, btab, relidx,
                                        wqkvT, wmergeT, w1T, w2T, battn);

  ingest_kernel<<<896, 256, 0, stream>>>(x, ln1_g, ln1_b, R1, R2);

  // attention path, 2 window-aligned chunks of 25088 tokens
  for (int c = 0; c < 2; ++c) {
    size_t r0 = (size_t)c * 25088;
    gemm_kernel<0, 4><<<dim3(3, 196), 512, 0, stream>>>(
        (const bf16*)(R2 + r0 * 256), wqkvT, bqkv, 768, 256, (bf16*)qkvc, nullptr);
    attn_kernel<<<4096, 64, 0, stream>>>(qkvc, battn, attnc);
    gemm_kernel<2, 2><<<dim3(2, 196), 256, 0, stream>>>(
        (const bf16*)attnc, wmergeT, bmerge, 256, 256, nullptr, R1 + r0 * 256);
  }

  // LN2 over full xw -> z
  ln2_kernel<<<NTOK / 4, 256, 0, stream>>>(R1, ln2_g, ln2_b, R2);

  // MLP, 2 chunks
  for (int c = 0; c < 2; ++c) {
    size_t r0 = (size_t)c * 25088;
    gemm_kernel<1, 4><<<dim3(4, 196), 512, 0, stream>>>(
        (const bf16*)(R2 + r0 * 256), w1T, b1, 1024, 256, (bf16*)hbuf, nullptr);
    gemm_kernel<2, 2><<<dim3(2, 196), 256, 0, stream>>>(
        (const bf16*)hbuf, w2T, b2, 256, 1024, nullptr, R1 + r0 * 256);
  }

  egress_kernel<<<896, 256, 0, stream>>>(R1, out);
}

// Round 5
// 285.599 us; speedup vs baseline: 1.9829x; 1.0199x over previous
//
#include <hip/hip_runtime.h>
#include <hip/hip_bf16.h>

#define B_      16
#define C_      256
#define H_      56
#define W_      56
#define HW_     3136
#define G_      64
#define P_      49
#define NTOK    50176
#define HEADS_  8
#define DH_     32
#define SCALE_  0.0625f
#define EPS_    1e-5f

typedef short bf16x8 __attribute__((ext_vector_type(8)));
typedef short bf16x4_t __attribute__((ext_vector_type(4)));
typedef float f32x4  __attribute__((ext_vector_type(4)));
using bf16 = __hip_bfloat16;

__device__ __forceinline__ void gload16(const void* g, void* l) {
  __builtin_amdgcn_global_load_lds((const __attribute__((address_space(1))) void*)g,
                                   (__attribute__((address_space(3))) void*)l, 16, 0, 0);
}
__device__ __forceinline__ float b2f(short s) {
  union { float f; unsigned u; } v; v.u = ((unsigned)(unsigned short)s) << 16; return v.f;
}
__device__ __forceinline__ short f2b(float f) {   // RNE
  union { float f; unsigned u; } v; v.f = f;
  unsigned r = (v.u + 0x7FFFu + ((v.u >> 16) & 1u)) >> 16;
  return (short)r;
}

// ---------------------------------------------------------------------------
// prep: weights -> [N][K] bf16; bias -> bt[h][key(64)][q*4+qni] bf16
// ---------------------------------------------------------------------------
__global__ __launch_bounds__(256)
void prep_kernel(const float* __restrict__ wqkv, const float* __restrict__ wmerge,
                 const float* __restrict__ w1, const float* __restrict__ w2,
                 const float* __restrict__ btab, const int* __restrict__ relidx,
                 bf16* __restrict__ wqkvT, bf16* __restrict__ wmergeT,
                 bf16* __restrict__ w1T, bf16* __restrict__ w2T,
                 short* __restrict__ bt)
{
  int idx = blockIdx.x * 256 + threadIdx.x;
  if (idx < 196608) { int n = idx >> 8, k = idx & 255;
    wqkvT[idx] = __float2bfloat16(wqkv[k * 768 + n]); return; }
  idx -= 196608;
  if (idx < 65536) { int n = idx >> 8, k = idx & 255;
    wmergeT[idx] = __float2bfloat16(wmerge[k * 256 + n]); return; }
  idx -= 65536;
  if (idx < 262144) { int n = idx >> 8, k = idx & 255;
    w1T[idx] = __float2bfloat16(w1[k * 1024 + n]); return; }
  idx -= 262144;
  if (idx < 262144) { int n = idx >> 10, k = idx & 1023;
    w2T[idx] = __float2bfloat16(w2[k * 256 + n]); return; }
  idx -= 262144;
  if (idx < 32768) {
    int h = idx >> 12, rest = idx & 4095;
    int key = rest >> 6, col = rest & 63;
    int q = col >> 2, qni = col & 3;
    int query = qni * 16 + q;
    float v = 0.f;
    if (key < P_ && query < P_) v = btab[relidx[query * P_ + key] * HEADS_ + h];
    bt[idx] = f2b(v);
  }
}

// ---------------------------------------------------------------------------
// ingest: block=(b,h). Phase1: float4-coalesced read of x[b][:][h][:],
// bf16 into LDS [56][260] transposed. Phase2: wave-per-token LN, contiguous
// 512B row writes of xtok (raw) and y (normalized).
// ---------------------------------------------------------------------------
__global__ __launch_bounds__(256)
void ingest_kernel(const float* __restrict__ x, const float* __restrict__ gam,
                   const float* __restrict__ bet, short* __restrict__ xtok,
                   short* __restrict__ y)
{
  __shared__ short Lt[56 * 260];
  const int h = blockIdx.x % 56, b = blockIdx.x / 56;
  const int tid = threadIdx.x;

  const float* xb = x + (size_t)b * 256 * HW_ + h * 56;
#pragma unroll
  for (int i = 0; i < 14; i++) {
    int idx = i * 256 + tid;
    int c = idx / 14, w4 = idx - c * 14;
    float4 v = *(const float4*)(xb + (size_t)c * HW_ + w4 * 4);
    Lt[(w4 * 4 + 0) * 260 + c] = f2b(v.x);
    Lt[(w4 * 4 + 1) * 260 + c] = f2b(v.y);
    Lt[(w4 * 4 + 2) * 260 + c] = f2b(v.z);
    Lt[(w4 * 4 + 3) * 260 + c] = f2b(v.w);
  }
  __syncthreads();

  const int lane = tid & 63, wv = tid >> 6;
  float4 gv = *(const float4*)(gam + lane * 4);
  float4 bv = *(const float4*)(bet + lane * 4);
  const int hdiv = h / 7, hmod = h - hdiv * 7;

  for (int t = 0; t < 14; t++) {
    int w = wv * 14 + t;
    bf16x4_t raw = *(const bf16x4_t*)&Lt[w * 260 + lane * 4];
    float f0 = b2f(raw[0]), f1 = b2f(raw[1]), f2 = b2f(raw[2]), f3 = b2f(raw[3]);
    float sum = f0 + f1 + f2 + f3;
    float sq  = f0*f0 + f1*f1 + f2*f2 + f3*f3;
#pragma unroll
    for (int off = 32; off > 0; off >>= 1) {
      sum += __shfl_xor(sum, off, 64);
      sq  += __shfl_xor(sq,  off, 64);
    }
    float mu = sum * (1.0f / 256.0f);
    float var = sq * (1.0f / 256.0f) - mu * mu;
    float rs = rsqrtf(var + EPS_);
    int wdiv = w / 7, wmod = w - wdiv * 7;
    int tok = b * HW_ + (hdiv * 8 + wdiv) * P_ + hmod * 7 + wmod;
    *(bf16x4_t*)(xtok + (size_t)tok * 256 + lane * 4) = raw;
    bf16x4_t o;
    o[0] = f2b((f0 - mu) * rs * gv.x + bv.x);
    o[1] = f2b((f1 - mu) * rs * gv.y + bv.y);
    o[2] = f2b((f2 - mu) * rs * gv.z + bv.z);
    o[3] = f2b((f3 - mu) * rs * gv.w + bv.w);
    *(bf16x4_t*)(y + (size_t)tok * 256 + lane * 4) = o;
  }
}

// ---------------------------------------------------------------------------
// ln2: xw (bf16 token-major) -> z bf16. wave per token.
// ---------------------------------------------------------------------------
__global__ __launch_bounds__(256)
void ln2_kernel(const short* __restrict__ xw, const float* __restrict__ gam,
                const float* __restrict__ bet, short* __restrict__ z)
{
  const int t = blockIdx.x * 4 + (threadIdx.x >> 6);
  const int lane = threadIdx.x & 63;
  bf16x4_t raw = *(const bf16x4_t*)(xw + (size_t)t * 256 + lane * 4);
  float v[4];
#pragma unroll
  for (int j = 0; j < 4; j++) v[j] = b2f(raw[j]);
  float sum = v[0] + v[1] + v[2] + v[3];
  float sq  = v[0]*v[0] + v[1]*v[1] + v[2]*v[2] + v[3]*v[3];
#pragma unroll
  for (int off = 32; off > 0; off >>= 1) {
    sum += __shfl_xor(sum, off, 64);
    sq  += __shfl_xor(sq,  off, 64);
  }
  float mu = sum * (1.0f / 256.0f);
  float var = sq * (1.0f / 256.0f) - mu * mu;
  float rs = rsqrtf(var + EPS_);
  bf16x4_t o;
#pragma unroll
  for (int j = 0; j < 4; j++) {
    int c = lane * 4 + j;
    o[j] = f2b((v[j] - mu) * rs * gam[c] + bet[c]);
  }
  *(bf16x4_t*)(z + (size_t)t * 256 + lane * 4) = o;
}

// ---------------------------------------------------------------------------
// egress: token-major bf16 -> BCHW f32 out
// ---------------------------------------------------------------------------
__global__ __launch_bounds__(256)
void egress_kernel(const short* __restrict__ outtok, float* __restrict__ out)
{
  const int h = blockIdx.x % 56, b = blockIdx.x / 56;
  const int w = threadIdx.x & 63, cblk = threadIdx.x >> 6;
  const bool act = w < 56;
  const int wcl = act ? w : 55;
  const int tok = b * HW_ + ((h / 7) * 8 + wcl / 7) * P_ + (h % 7) * 7 + (wcl % 7);
  const short* src = outtok + (size_t)tok * 256 + cblk * 64;
  float* dst = out + ((size_t)b * 256 + cblk * 64) * HW_ + h * 56 + w;
#pragma unroll
  for (int j0 = 0; j0 < 64; j0 += 8) {
    bf16x8 r = *(const bf16x8*)(src + j0);
#pragma unroll
    for (int jj = 0; jj < 8; jj++)
      if (act) dst[(size_t)(j0 + jj) * HW_] = b2f(r[jj]);
  }
}

// ---------------------------------------------------------------------------
// attention (MFMA): one wave per (window, head), chunk-local pointers
// ---------------------------------------------------------------------------
__global__ __launch_bounds__(64)
void attn_kernel(const short* __restrict__ qkv, const short* __restrict__ bt,
                 short* __restrict__ out)
{
  __shared__ short Pbuf[64 * 72];
  const int bid = blockIdx.x;
  const int h = bid & 7;
  const int t0 = (bid >> 3) * P_;
  const int lane = threadIdx.x;
  const int g = lane >> 4, q = lane & 15;

  const short* qb = qkv + (size_t)t0 * 768 + h * 32;

  bf16x8 vf[2][2];
#pragma unroll
  for (int kkt = 0; kkt < 2; kkt++)
#pragma unroll
    for (int n2 = 0; n2 < 2; n2++)
#pragma unroll
      for (int jj = 0; jj < 8; jj++) {
        int key = kkt * 32 + 8 * g + jj; key = key > 48 ? 48 : key;
        vf[kkt][n2][jj] = qb[(size_t)key * 768 + 512 + n2 * 16 + q];
      }

  bf16x8 kf[4], qf[4];
#pragma unroll
  for (int mi = 0; mi < 4; mi++) {
    int r_ = mi * 16 + q; r_ = r_ > 48 ? 48 : r_;
    kf[mi] = *(const bf16x8*)(qb + (size_t)r_ * 768 + 256 + 8 * g);
  }
#pragma unroll
  for (int ni = 0; ni < 4; ni++) {
    int r_ = ni * 16 + q; r_ = r_ > 48 ? 48 : r_;
    qf[ni] = *(const bf16x8*)(qb + (size_t)r_ * 768 + 8 * g);
  }

  f32x4 sacc[4][4] = {};
#pragma unroll
  for (int mi = 0; mi < 4; mi++)
#pragma unroll
    for (int ni = 0; ni < 4; ni++)
      sacc[mi][ni] = __builtin_amdgcn_mfma_f32_16x16x32_bf16(kf[mi], qf[ni], sacc[mi][ni], 0, 0, 0);

  float mx[4] = {-1e30f, -1e30f, -1e30f, -1e30f};
  const short* btb = bt + (size_t)(h * 64) * 64 + q * 4;
#pragma unroll
  for (int mi = 0; mi < 4; mi++)
#pragma unroll
    for (int r = 0; r < 4; r++) {
      int key = mi * 16 + 4 * g + r;
      bf16x4_t bv = *(const bf16x4_t*)(btb + key * 64);
      bool valid = key < P_;
#pragma unroll
      for (int ni = 0; ni < 4; ni++) {
        float s = valid ? fmaf(sacc[mi][ni][r], SCALE_, b2f(bv[ni])) : -1e30f;
        sacc[mi][ni][r] = s;
        mx[ni] = fmaxf(mx[ni], s);
      }
    }
#pragma unroll
  for (int ni = 0; ni < 4; ni++) {
    mx[ni] = fmaxf(mx[ni], __shfl_xor(mx[ni], 16, 64));
    mx[ni] = fmaxf(mx[ni], __shfl_xor(mx[ni], 32, 64));
  }
  float sm[4] = {0.f, 0.f, 0.f, 0.f};
#pragma unroll
  for (int mi = 0; mi < 4; mi++)
#pragma unroll
    for (int ni = 0; ni < 4; ni++)
#pragma unroll
      for (int r = 0; r < 4; r++) {
        float p = __expf(sacc[mi][ni][r] - mx[ni]);
        sacc[mi][ni][r] = p;
        sm[ni] += p;
      }
#pragma unroll
  for (int ni = 0; ni < 4; ni++) {
    sm[ni] += __shfl_xor(sm[ni], 16, 64);
    sm[ni] += __shfl_xor(sm[ni], 32, 64);
    sm[ni] = 1.0f / sm[ni];
  }
#pragma unroll
  for (int ni = 0; ni < 4; ni++)
#pragma unroll
    for (int mi = 0; mi < 4; mi++) {
      bf16x4_t pv;
#pragma unroll
      for (int r = 0; r < 4; r++) pv[r] = f2b(sacc[mi][ni][r] * sm[ni]);
      *(bf16x4_t*)&Pbuf[(ni * 16 + q) * 72 + mi * 16 + 4 * g] = pv;
    }
  __syncthreads();

  f32x4 oacc[4][2] = {};
#pragma unroll
  for (int kkt = 0; kkt < 2; kkt++) {
    bf16x8 paf[4];
#pragma unroll
    for (int qi = 0; qi < 4; qi++)
      paf[qi] = *(const bf16x8*)&Pbuf[(qi * 16 + q) * 72 + kkt * 32 + 8 * g];
#pragma unroll
    for (int qi = 0; qi < 4; qi++)
#pragma unroll
      for (int n2 = 0; n2 < 2; n2++)
        oacc[qi][n2] = __builtin_amdgcn_mfma_f32_16x16x32_bf16(paf[qi], vf[kkt][n2], oacc[qi][n2], 0, 0, 0);
  }

  short* ob = out + (size_t)t0 * 256 + h * 32;
#pragma unroll
  for (int qi = 0; qi < 4; qi++)
#pragma unroll
    for (int r = 0; r < 4; r++) {
      int query = qi * 16 + 4 * g + r;
      if (query < P_) {
#pragma unroll
        for (int n2 = 0; n2 < 2; n2++)
          ob[(size_t)query * 256 + n2 * 16 + q] = f2b(oacc[qi][n2][r]);
      }
    }
}

// ---------------------------------------------------------------------------
// GEMM: BM=128, BN=64*WN, threads=128*WN (WN=2 or 4), 16x16x32 MFMA.
// DOUBLE-BUFFERED LDS, one barrier per K-step (T3-minimum 2-phase):
//   iter t: STAGE(buf^1, t+1) issued first; ds_read+MFMA on buf; __syncthreads
// (sync drains vmcnt for the stage + lgkmcnt; prev-iter barrier makes the
//  overwrite of buf^1 safe). Source-col XOR pre-swizzle + swizzled ds_read (T2).
// EPI 0: bf16 store   EPI 1: gelu -> bf16   EPI 2: in-place residual add
// ---------------------------------------------------------------------------
template<int EPI, int WN>
__global__ __launch_bounds__(128 * WN)
void gemm_kernel(const bf16* __restrict__ A, const bf16* __restrict__ Wt,
                 const float* __restrict__ bias, int N, int K,
                 bf16* __restrict__ outb, short* __restrict__ res_io)
{
  constexpr int THREADS = 128 * WN;
  constexpr int BN = 64 * WN;
  constexpr int RPP = THREADS / 4;      // rows staged per pass
  constexpr int APASS = 128 / RPP;      // 2 (WN=2) or 1 (WN=4)
  __shared__ __align__(16) bf16 As[2][128 * 32];
  __shared__ __align__(16) bf16 Bs[2][BN * 32];
  const int tid = threadIdx.x;
  const int lane = tid & 63;
  const int wave = tid >> 6;
  const int wr = wave / WN, wc = wave % WN;
  const int bm = blockIdx.y * 128, bn = blockIdx.x * BN;

  f32x4 acc[4][4] = {};

  const int trow = tid >> 2;
  const int tcol = ((tid & 3) ^ ((tid >> 3) & 3)) * 8;   // swizzled source chunk
  const bf16* aA[APASS];
#pragma unroll
  for (int p = 0; p < APASS; p++)
    aA[p] = A + (size_t)(bm + p * RPP + trow) * K + tcol;
  const bf16* aB0 = Wt + (size_t)(bn + trow) * K + tcol;
  const bf16* aB1 = Wt + (size_t)(bn + RPP + trow) * K + tcol;
  const int dOff = tid * 8;

  const int kc_sw = ((lane >> 4) ^ ((lane >> 1) & 3)) * 8;  // swizzled read chunk
  const int rA = wr * 64 + (lane & 15);
  const int rB = wc * 64 + (lane & 15);

  const int nt = K >> 5;

  // prologue: stage tile 0 into buffer 0
#pragma unroll
  for (int p = 0; p < APASS; p++) gload16(aA[p], &As[0][p * RPP * 32 + dOff]);
  gload16(aB0, &Bs[0][dOff]);
  gload16(aB1, &Bs[0][RPP * 32 + dOff]);
  __syncthreads();

  for (int t = 0; t < nt; ++t) {
    const int cur = t & 1;
    if (t + 1 < nt) {                     // stage next tile into other buffer
      const int k1 = (t + 1) << 5;
      const int nxt = cur ^ 1;
#pragma unroll
      for (int p = 0; p < APASS; p++) gload16(aA[p] + k1, &As[nxt][p * RPP * 32 + dOff]);
      gload16(aB0 + k1, &Bs[nxt][dOff]);
      gload16(aB1 + k1, &Bs[nxt][RPP * 32 + dOff]);
    }
    bf16x8 af[4], bfr[4];
#pragma unroll
    for (int i = 0; i < 4; i++) {
      af[i]  = *(const bf16x8*)(&As[cur][(rA + i * 16) * 32 + kc_sw]);
      bfr[i] = *(const bf16x8*)(&Bs[cur][(rB + i * 16) * 32 + kc_sw]);
    }
#pragma unroll
    for (int mi = 0; mi < 4; mi++)
#pragma unroll
      for (int ni = 0; ni < 4; ni++)
        acc[mi][ni] = __builtin_amdgcn_mfma_f32_16x16x32_bf16(af[mi], bfr[ni], acc[mi][ni], 0, 0, 0);
    __syncthreads();   // drains stage vmcnt + lds lgkmcnt; one barrier per K-step
  }

#pragma unroll
  for (int mi = 0; mi < 4; mi++) {
#pragma unroll
    for (int ni = 0; ni < 4; ni++) {
#pragma unroll
      for (int r = 0; r < 4; r++) {
        const int row = bm + wr * 64 + mi * 16 + (lane >> 4) * 4 + r;
        const int col = bn + wc * 64 + ni * 16 + (lane & 15);
        float v = acc[mi][ni][r] + bias[col];
        if (EPI == 0) {
          outb[(size_t)row * N + col] = __float2bfloat16(v);
        } else if (EPI == 1) {
          float gv = 0.5f * v * (1.0f + erff(v * 0.70710678118f));
          outb[(size_t)row * N + col] = __float2bfloat16(gv);
        } else {
          size_t o = (size_t)row * 256 + col;
          res_io[o] = f2b(v + b2f(res_io[o]));
        }
      }
    }
  }
}

// ---------------------------------------------------------------------------
extern "C" void kernel_launch(void* const* d_in, const int* in_sizes, int n_in,
                              void* d_out, int out_size, void* d_ws, size_t ws_size,
                              hipStream_t stream)
{
  const float* x      = (const float*)d_in[0];
  const float* ln1_g  = (const float*)d_in[1];
  const float* ln1_b  = (const float*)d_in[2];
  const float* wqkv   = (const float*)d_in[3];
  const float* bqkv   = (const float*)d_in[4];
  const float* wmerge = (const float*)d_in[5];
  const float* bmerge = (const float*)d_in[6];
  const float* btab   = (const float*)d_in[7];
  const float* ln2_g  = (const float*)d_in[8];
  const float* ln2_b  = (const float*)d_in[9];
  const float* w1     = (const float*)d_in[10];
  const float* b1     = (const float*)d_in[11];
  const float* w2     = (const float*)d_in[12];
  const float* b2     = (const float*)d_in[13];
  const int*   relidx = (const int*)d_in[14];
  float* out = (float*)d_out;

  char* ws = (char*)d_ws;
  bf16*  wqkvT   = (bf16*)(ws);                   // 393,216
  bf16*  wmergeT = (bf16*)(ws + 393216);          // 131,072
  bf16*  w1T     = (bf16*)(ws + 524288);          // 524,288
  bf16*  w2T     = (bf16*)(ws + 1048576);         // 524,288
  short* battn   = (short*)(ws + 1572864);        // 65,536
  short* R1      = (short*)(ws + 1638400);        // 25,690,112 residual stream
  short* R2      = (short*)(ws + 27328512);       // 25,690,112 y / z
  short* qkvc    = (short*)(ws + 53018624);       // 38,535,168 (half-chunk qkv)
  short* attnc   = (short*)(ws + 91553792);       // 12,845,056
  short* hbuf    = (short*)(ws + 53018624);       // 51,380,224 (aliases qkvc+attnc)
  // end: 104,398,848

  prep_kernel<<<3200, 256, 0, stream>>>(wqkv, wmerge, w1, w2, btab, relidx,
                                        wqkvT, wmergeT, w1T, w2T, battn);

  ingest_kernel<<<896, 256, 0, stream>>>(x, ln1_g, ln1_b, R1, R2);

  // attention path, 2 window-aligned chunks of 25088 tokens
  for (int c = 0; c < 2; ++c) {
    size_t r0 = (size_t)c * 25088;
    gemm_kernel<0, 4><<<dim3(3, 196), 512, 0, stream>>>(
        (const bf16*)(R2 + r0 * 256), wqkvT, bqkv, 768, 256, (bf16*)qkvc, nullptr);
    attn_kernel<<<4096, 64, 0, stream>>>(qkvc, battn, attnc);
    gemm_kernel<2, 2><<<dim3(2, 196), 256, 0, stream>>>(
        (const bf16*)attnc, wmergeT, bmerge, 256, 256, nullptr, R1 + r0 * 256);
  }

  // LN2 over full xw -> z
  ln2_kernel<<<NTOK / 4, 256, 0, stream>>>(R1, ln2_g, ln2_b, R2);

  // MLP, 2 chunks
  for (int c = 0; c < 2; ++c) {
    size_t r0 = (size_t)c * 25088;
    gemm_kernel<1, 4><<<dim3(4, 196), 512, 0, stream>>>(
        (const bf16*)(R2 + r0 * 256), w1T, b1, 1024, 256, (bf16*)hbuf, nullptr);
    gemm_kernel<2, 2><<<dim3(2, 196), 256, 0, stream>>>(
        (const bf16*)hbuf, w2T, b2, 256, 1024, nullptr, R1 + r0 * 256);
  }

  egress_kernel<<<896, 256, 0, stream>>>(R1, out);
}